// Round 8
// baseline (4946.592 us; speedup 1.0000x reference)
//
#include <hip/hip_runtime.h>
#include <hip/hip_bf16.h>
#include <cstdint>

#define DEV __device__ __forceinline__

// Exact per-op-rounded squared distance, matching numpy's ((dx^2+dy^2)+dz^2)
// with no FMA contraction. All index decisions (FPS/ball/kNN) depend on this
// being bit-identical to the f32 reference.
DEV float sqdist(float ax, float ay, float az, float bx, float by, float bz) {
    float dx = __fsub_rn(ax, bx), dy = __fsub_rn(ay, by), dz = __fsub_rn(az, bz);
    return __fadd_rn(__fadd_rn(__fmul_rn(dx, dx), __fmul_rn(dy, dy)), __fmul_rn(dz, dz));
}

// Same exact semantics (plain IEEE mul/add, contraction OFF) but written so
// the SLP vectorizer may pack independent points into v_pk_* ops.
DEV float sqdist_nc(float ax, float ay, float az, float bx, float by, float bz) {
#pragma clang fp contract(off)
    float dx = ax - bx, dy = ay - by, dz = az - bz;
    return (dx * dx + dy * dy) + dz * dz;
}

DEV unsigned short f2bf(float f) {  // RNE f32 -> bf16 (ws feature storage only)
    unsigned int u = __float_as_uint(f);
    u += 0x7fffu + ((u >> 16) & 1u);
    return (unsigned short)(u >> 16);
}

DEV float bf2f(unsigned short u) { return __uint_as_float(((unsigned int)u) << 16); }

// ---- fast wave reduces: DPP row_ror within 16 lanes (VALU) + 2 LDS shfl ----
template <int CTRL>
DEV int dpp_i(int v) { return __builtin_amdgcn_update_dpp(v, v, CTRL, 0xf, 0xf, false); }
template <int CTRL>
DEV float dpp_f(float v) { return __int_as_float(dpp_i<CTRL>(__float_as_int(v))); }

DEV void comb_max(float& v, int& i, float ov, int oi) {
    if (ov > v || (ov == v && oi < i)) { v = ov; i = oi; }
}
DEV void comb_min(float& v, int& i, float ov, int oi) {
    if (ov < v || (ov == v && oi < i)) { v = ov; i = oi; }
}
// full-wave lexicographic argmax: (max value, min index). Rotate-reduce
// covers each 16-lane row, then xor16/xor32 combine rows.
DEV void wave_argmax(float& v, int& i) {
    comb_max(v, i, dpp_f<0x128>(v), dpp_i<0x128>(i));  // row_ror:8
    comb_max(v, i, dpp_f<0x124>(v), dpp_i<0x124>(i));  // row_ror:4
    comb_max(v, i, dpp_f<0x122>(v), dpp_i<0x122>(i));  // row_ror:2
    comb_max(v, i, dpp_f<0x121>(v), dpp_i<0x121>(i));  // row_ror:1
    comb_max(v, i, __shfl_xor(v, 16, 64), __shfl_xor(i, 16, 64));
    comb_max(v, i, __shfl_xor(v, 32, 64), __shfl_xor(i, 32, 64));
}
DEV void wave_argmin(float& v, int& i) {
    comb_min(v, i, dpp_f<0x128>(v), dpp_i<0x128>(i));
    comb_min(v, i, dpp_f<0x124>(v), dpp_i<0x124>(i));
    comb_min(v, i, dpp_f<0x122>(v), dpp_i<0x122>(i));
    comb_min(v, i, dpp_f<0x121>(v), dpp_i<0x121>(i));
    comb_min(v, i, __shfl_xor(v, 16, 64), __shfl_xor(i, 16, 64));
    comb_min(v, i, __shfl_xor(v, 32, 64), __shfl_xor(i, 32, 64));
}

// Output offsets (f32 elements) in return order.
enum : int {
    O_X1 = 0, O_X2 = 12288, O_X3 = 15360,
    O_I1 = 16128, O_I2 = 20224, O_I3 = 21248,
    O_U0 = 21504, O_U1 = 545792, O_U2 = 807936, O_U3 = 939008
};

// ---------------------------------------------------------------- init ------
__global__ __launch_bounds__(256) void k_init(const float* __restrict__ pc,
                                              const float* __restrict__ feat,
                                              const float* __restrict__ w0,
                                              const float* __restrict__ b0,
                                              float* __restrict__ xyz,
                                              unsigned short* __restrict__ f0) {
    const int N = 8192;
    int i = blockIdx.x * blockDim.x + threadIdx.x;
    if (i >= 2 * N) return;
    int b = i / N, n = i % N;
    float fx0 = feat[(b * 3 + 0) * N + n];
    float fx1 = feat[(b * 3 + 1) * N + n];
    float fx2 = feat[(b * 3 + 2) * N + n];
    xyz[i * 3 + 0] = pc[(b * 3 + 0) * N + n];
    xyz[i * 3 + 1] = pc[(b * 3 + 1) * N + n];
    xyz[i * 3 + 2] = pc[(b * 3 + 2) * N + n];
#pragma unroll
    for (int o = 0; o < 32; o++) {
        float acc = b0[o];
        acc = fmaf(w0[o * 3 + 0], fx0, acc);
        acc = fmaf(w0[o * 3 + 1], fx1, acc);
        acc = fmaf(w0[o * 3 + 2], fx2, acc);
        f0[(size_t)i * 32 + o] = f2bf(fmaxf(acc, 0.f));
    }
}

// ----------------------------------------------------------------- FPS ------
// One block per batch, T=512 -> 2 waves/SIMD for latency hiding. Points +
// dmin in registers; xyz mirrored in LDS so the winner's coords are a
// broadcast LDS read. Per iteration (<=1 barrier):
//   fmax tree over P -> eq-scan + min tree (local i) -> DPP+shfl wave argmax
//   -> [W>1: u64 slot write, barrier, serial W-slot reduce] -> coords from
//   LDS -> packed-f32 dmin update. Key (dist<<32 | ~idx) == numpy first-max.
template <int N, int M, int T>
__global__ __launch_bounds__(T, 1) void k_fps(const float* __restrict__ xyz,
                                              int* __restrict__ idx_out) {
    constexpr int P = N / T;
    constexpr int W = T / 64;
    int b = blockIdx.x;
    const float* X = xyz + (size_t)b * N * 3;
    int t = threadIdx.x;
    int w = t >> 6;
    __shared__ float sx[N], sy[N], sz[N];
    __shared__ unsigned long long skey[2][W > 1 ? W : 1];
    float px[P], py[P], pz[P], dmin[P];
    float c0x = X[0], c0y = X[1], c0z = X[2];
#pragma unroll
    for (int i = 0; i < P; i++) {
        int p = i * T + t;
        px[i] = X[p * 3 + 0];
        py[i] = X[p * 3 + 1];
        pz[i] = X[p * 3 + 2];
        sx[p] = px[i]; sy[p] = py[i]; sz[p] = pz[i];
        dmin[i] = sqdist(px[i], py[i], pz[i], c0x, c0y, c0z);
    }
    if (t == 0) idx_out[b * M] = 0;
    if constexpr (W == 1) __builtin_amdgcn_s_waitcnt(0);  // lgkm drain before first sx read
    for (int j = 1; j < M; j++) {
        // local max value: explicit tree (independent ops, depth log2 P)
        float mv[P];
#pragma unroll
        for (int i = 0; i < P; i++) mv[i] = dmin[i];
#pragma unroll
        for (int s = P / 2; s >= 1; s >>= 1)
#pragma unroll
            for (int i = 0; i < s; i++) mv[i] = fmaxf(mv[i], mv[i + s]);
        float bv = mv[0];
        // first (=min) local slot achieving bv -> global index i*T + t
        int ii[P];
#pragma unroll
        for (int i = 0; i < P; i++) ii[i] = (dmin[i] == bv) ? i : 0x7fffffff;
#pragma unroll
        for (int s = P / 2; s >= 1; s >>= 1)
#pragma unroll
            for (int i = 0; i < s; i++) ii[i] = min(ii[i], ii[i + s]);
        int bi = (ii[0] == 0x7fffffff) ? 0x7fffffff : ii[0] * T + t;
        wave_argmax(bv, bi);
        int gi;
        if constexpr (W > 1) {
            unsigned long long key =
                ((unsigned long long)__float_as_uint(bv) << 32) | (unsigned int)~bi;
            int sl = j & 1;
            if ((t & 63) == 0) skey[sl][w] = key;
            __syncthreads();
            unsigned long long gk = skey[sl][0];
#pragma unroll
            for (int u = 1; u < W; u++) {
                unsigned long long ok = skey[sl][u];
                gk = ok > gk ? ok : gk;
            }
            gi = (int)~(unsigned int)gk;
        } else {
            gi = bi;
        }
        if (t == 0) idx_out[b * M + j] = gi;
        float cx = sx[gi], cy = sy[gi], cz = sz[gi];  // broadcast, conflict-free
#pragma unroll
        for (int i = 0; i < P; i++)
            dmin[i] = fminf(dmin[i], sqdist_nc(px[i], py[i], pz[i], cx, cy, cz));
        // W>1: no second barrier needed — next iteration writes the OTHER
        // slot parity; reaching that write implies passing this barrier.
    }
}

// -------------------------------------------------------------- gather ------
__global__ __launch_bounds__(256) void k_gather(const float* __restrict__ xyz_src,
                                                const int* __restrict__ idx,
                                                float* __restrict__ xyz_dst,
                                                int NS, int M) {
    int i = blockIdx.x * blockDim.x + threadIdx.x;
    if (i >= 2 * M) return;
    int b = i / M;
    int id = idx[i] & (NS - 1);
    xyz_dst[i * 3 + 0] = xyz_src[((size_t)b * NS + id) * 3 + 0];
    xyz_dst[i * 3 + 1] = xyz_src[((size_t)b * NS + id) * 3 + 1];
    xyz_dst[i * 3 + 2] = xyz_src[((size_t)b * NS + id) * 3 + 2];
}

// ------------------------------------------------------------- SetConv ------
template <int NS, int CF, int CMID, int COUT>
__global__ __launch_bounds__(128) void k_setconv(
    const float* __restrict__ X, const unsigned short* __restrict__ F,
    const float* __restrict__ C, const float* __restrict__ w1,
    const float* __restrict__ b1, const float* __restrict__ w2,
    const float* __restrict__ b2, unsigned short* __restrict__ fout,
    float r2, int M) {
    constexpr int CIN = 3 + CF;
    constexpr int K = 16;
    constexpr int M8 = CMID / 8;
    constexpr int O8 = COUT / 8;
    int q = blockIdx.x, b = blockIdx.y;
    int blk = b * M + q;
    const float* Xb = X + (size_t)b * NS * 3;
    const unsigned short* Fb = F + (size_t)b * NS * CF;
    int tid = threadIdx.x;
    __shared__ int s_n[K];
    __shared__ int s_cnt;
    __shared__ float s_h[K][CIN];
    __shared__ float s_mid[K][CMID];
    __shared__ float s_pool[2][COUT];
    float cx = C[(size_t)blk * 3 + 0], cy = C[(size_t)blk * 3 + 1], cz = C[(size_t)blk * 3 + 2];
    if (tid < 64) {
        int lane = tid;
        int cnt = 0;
        for (int base = 0; base < NS; base += 64) {
            int p = base + lane;
            float d2 = sqdist(Xb[p * 3], Xb[p * 3 + 1], Xb[p * 3 + 2], cx, cy, cz);
            bool in = (d2 <= r2);
            unsigned long long msk = __ballot(in);
            if (in) {
                int pos = cnt + __popcll(msk & ((1ull << lane) - 1ull));
                if (pos < K) s_n[pos] = p;
            }
            cnt += __popcll(msk);
            if (cnt >= K) break;
        }
        if (lane == 0) s_cnt = cnt < K ? cnt : K;
    }
    __syncthreads();
    int cnt = s_cnt;
    if (tid >= cnt && tid < K) s_n[tid] = s_n[0];  // pad (center itself always hits)
    __syncthreads();
    for (int tIdx = tid; tIdx < K * CIN; tIdx += 128) {
        int n = tIdx / CIN, c = tIdx % CIN;
        int gi = s_n[n];
        float v;
        if (c < 3) v = __fsub_rn(Xb[gi * 3 + c], (c == 0 ? cx : (c == 1 ? cy : cz)));
        else v = bf2f(Fb[(size_t)gi * CF + (c - 3)]);
        s_h[n][c] = v;
    }
    __syncthreads();
    int n = tid >> 3, sub = tid & 7;
#pragma unroll
    for (int j = 0; j < M8; j++) {
        int m = sub * M8 + j;
        float acc = b1[m];
#pragma unroll 4
        for (int c = 0; c < CIN; c++) acc = fmaf(w1[m * CIN + c], s_h[n][c], acc);
        s_mid[n][m] = fmaxf(acc, 0.f);
    }
    __syncthreads();
    float vals[O8];
#pragma unroll
    for (int j = 0; j < O8; j++) {
        int o = sub * O8 + j;
        float acc = b2[o];
#pragma unroll 4
        for (int c = 0; c < CMID; c++) acc = fmaf(w2[o * CMID + c], s_mid[n][c], acc);
        vals[j] = fmaxf(acc, 0.f);
    }
#pragma unroll
    for (int j = 0; j < O8; j++) {
        vals[j] = fmaxf(vals[j], dpp_f<0x128>(vals[j]));      // == xor 8 within rows
        vals[j] = fmaxf(vals[j], __shfl_xor(vals[j], 16, 64));
        vals[j] = fmaxf(vals[j], __shfl_xor(vals[j], 32, 64));
    }
    int lw = tid & 63, wv = tid >> 6;
    if (lw < 8) {
#pragma unroll
        for (int j = 0; j < O8; j++) s_pool[wv][lw * O8 + j] = vals[j];
    }
    __syncthreads();
    if (tid < 8) {
#pragma unroll
        for (int j = 0; j < O8; j++) {
            int o = tid * O8 + j;
            fout[(size_t)blk * COUT + o] = f2bf(fmaxf(s_pool[0][o], s_pool[1][o]));
        }
    }
}

// ------------------------------------------------------------ SetUpConv -----
template <int S, int CS, int CMID, int CD, int COUT, bool TRANS>
__global__ __launch_bounds__(64) void k_upconv(
    const float* __restrict__ SX, const float* __restrict__ DX,
    const void* __restrict__ SFv, const unsigned short* __restrict__ DF,
    const float* __restrict__ w1, const float* __restrict__ b1,
    const float* __restrict__ w2, const float* __restrict__ b2,
    float* __restrict__ out, int o_off, int ND) {
    constexpr int K = 8;
    constexpr int CIN = 3 + CS;
    constexpr int CIN2 = CMID + CD;
    constexpr int M8 = CMID / 8;
    int q = blockIdx.x, b = blockIdx.y;
    int blk = b * ND + q;
    int lane = threadIdx.x;
    const float* SXb = SX + (size_t)b * S * 3;
    float qx = DX[(size_t)blk * 3], qy = DX[(size_t)blk * 3 + 1], qz = DX[(size_t)blk * 3 + 2];
    __shared__ int s_k[K];
    __shared__ float s_h[K][CIN];
    __shared__ float s_in2[CIN2];
    float bd[K];
    int bi[K];
#pragma unroll
    for (int i = 0; i < K; i++) { bd[i] = 3.0e38f; bi[i] = 0x7fffffff; }
    for (int p = lane; p < S; p += 64) {
        float d2 = sqdist(SXb[p * 3], SXb[p * 3 + 1], SXb[p * 3 + 2], qx, qy, qz);
        if (d2 < bd[K - 1] || (d2 == bd[K - 1] && p < bi[K - 1])) {
            bd[K - 1] = d2; bi[K - 1] = p;
#pragma unroll
            for (int j = K - 1; j > 0; j--) {
                bool sw = (bd[j] < bd[j - 1]) || (bd[j] == bd[j - 1] && bi[j] < bi[j - 1]);
                if (sw) {
                    float tv = bd[j]; bd[j] = bd[j - 1]; bd[j - 1] = tv;
                    int ti = bi[j]; bi[j] = bi[j - 1]; bi[j - 1] = ti;
                }
            }
        }
    }
    for (int r = 0; r < K; r++) {
        float vv = bd[0]; int vi = bi[0];
        wave_argmin(vv, vi);
        if (lane == 0) s_k[r] = vi;
        if (vi == bi[0]) {  // unique owner lane pops its head
#pragma unroll
            for (int j = 0; j < K - 1; j++) { bd[j] = bd[j + 1]; bi[j] = bi[j + 1]; }
            bd[K - 1] = 3.0e38f; bi[K - 1] = 0x7fffffff;
        }
    }
    __syncthreads();
    for (int tIdx = lane; tIdx < K * CIN; tIdx += 64) {
        int n = tIdx / CIN, c = tIdx % CIN;
        int gi = s_k[n];
        float v;
        if (c < 3) v = __fsub_rn(SXb[gi * 3 + c], (c == 0 ? qx : (c == 1 ? qy : qz)));
        else if (TRANS) v = ((const float*)SFv)[((size_t)b * CS + (c - 3)) * S + gi];
        else v = bf2f(((const unsigned short*)SFv)[((size_t)b * S + gi) * CS + (c - 3)]);
        s_h[n][c] = v;
    }
    for (int c = lane; c < CD; c += 64) s_in2[CMID + c] = bf2f(DF[(size_t)blk * CD + c]);
    __syncthreads();
    int n = lane >> 3, sub = lane & 7;
    float vals[M8];
#pragma unroll
    for (int j = 0; j < M8; j++) {
        int m = sub * M8 + j;
        float acc = b1[m];
#pragma unroll 4
        for (int c = 0; c < CIN; c++) acc = fmaf(w1[m * CIN + c], s_h[n][c], acc);
        vals[j] = fmaxf(acc, 0.f);
    }
#pragma unroll
    for (int j = 0; j < M8; j++) {
        vals[j] = fmaxf(vals[j], dpp_f<0x128>(vals[j]));
        vals[j] = fmaxf(vals[j], __shfl_xor(vals[j], 16, 64));
        vals[j] = fmaxf(vals[j], __shfl_xor(vals[j], 32, 64));
    }
    if (lane < 8) {
#pragma unroll
        for (int j = 0; j < M8; j++) s_in2[lane * M8 + j] = vals[j];
    }
    __syncthreads();
    for (int o = lane; o < COUT; o += 64) {
        float acc = b2[o];
#pragma unroll 4
        for (int c = 0; c < CIN2; c++) acc = fmaf(w2[o * CIN2 + c], s_in2[c], acc);
        out[o_off + ((size_t)b * COUT + o) * ND + q] = fmaxf(acc, 0.f);
    }
}

// ------------------------------------------------------------- finalize -----
__global__ __launch_bounds__(256) void k_finalize(
    const float* __restrict__ xyz1, const float* __restrict__ xyz2,
    const float* __restrict__ xyz3, const int* __restrict__ idx1,
    const int* __restrict__ idx2, const int* __restrict__ idx3,
    float* __restrict__ out) {
    int i = blockIdx.x * blockDim.x + threadIdx.x;
    const float* xs;
    const int* is;
    int M, ox, oi, j;
    if (i < 4096) { xs = xyz1; is = idx1; M = 2048; ox = O_X1; oi = O_I1; j = i; }
    else if (i < 5120) { xs = xyz2; is = idx2; M = 512; ox = O_X2; oi = O_I2; j = i - 4096; }
    else if (i < 5376) { xs = xyz3; is = idx3; M = 128; ox = O_X3; oi = O_I3; j = i - 5120; }
    else return;
    int b = j / M, m = j % M;
    out[ox + (b * 3 + 0) * M + m] = xs[j * 3 + 0];
    out[ox + (b * 3 + 1) * M + m] = xs[j * 3 + 1];
    out[ox + (b * 3 + 2) * M + m] = xs[j * 3 + 2];
    out[oi + j] = (float)is[j];
}

// ---------------------------------------------------------------- launch ----
extern "C" void kernel_launch(void* const* d_in, const int* in_sizes, int n_in,
                              void* d_out, int out_size, void* d_ws, size_t ws_size,
                              hipStream_t stream) {
    const float* pc = (const float*)d_in[0];
    const float* feat = (const float*)d_in[1];
    const float* w0 = (const float*)d_in[2];
    const float* b0v = (const float*)d_in[3];
    const float* sc1w1 = (const float*)d_in[4];  const float* sc1b1 = (const float*)d_in[5];
    const float* sc1w2 = (const float*)d_in[6];  const float* sc1b2 = (const float*)d_in[7];
    const float* sc2w1 = (const float*)d_in[8];  const float* sc2b1 = (const float*)d_in[9];
    const float* sc2w2 = (const float*)d_in[10]; const float* sc2b2 = (const float*)d_in[11];
    const float* sc3w1 = (const float*)d_in[12]; const float* sc3b1 = (const float*)d_in[13];
    const float* sc3w2 = (const float*)d_in[14]; const float* sc3b2 = (const float*)d_in[15];
    const float* sc4w1 = (const float*)d_in[16]; const float* sc4b1 = (const float*)d_in[17];
    const float* sc4w2 = (const float*)d_in[18]; const float* sc4b2 = (const float*)d_in[19];
    const float* up4w1 = (const float*)d_in[20]; const float* up4b1 = (const float*)d_in[21];
    const float* up4w2 = (const float*)d_in[22]; const float* up4b2 = (const float*)d_in[23];
    const float* up3w1 = (const float*)d_in[24]; const float* up3b1 = (const float*)d_in[25];
    const float* up3w2 = (const float*)d_in[26]; const float* up3b2 = (const float*)d_in[27];
    const float* up2w1 = (const float*)d_in[28]; const float* up2b1 = (const float*)d_in[29];
    const float* up2w2 = (const float*)d_in[30]; const float* up2b2 = (const float*)d_in[31];
    const float* up1w1 = (const float*)d_in[32]; const float* up1b1 = (const float*)d_in[33];
    const float* up1w2 = (const float*)d_in[34]; const float* up1b2 = (const float*)d_in[35];
    float* out = (float*)d_out;

    char* ws = (char*)d_ws;
    size_t off = 0;
    auto A = [&](size_t bytes) -> char* {
        char* p = ws + off;
        off += (bytes + 255) & ~(size_t)255;
        return p;
    };
    float* xyz  = (float*)A((size_t)2 * 8192 * 3 * 4);
    int* idx1   = (int*)A((size_t)2 * 2048 * 4);
    int* idx2   = (int*)A((size_t)2 * 512 * 4);
    int* idx3   = (int*)A((size_t)2 * 128 * 4);
    int* idx4   = (int*)A((size_t)2 * 64 * 4);
    float* xyz1 = (float*)A((size_t)2 * 2048 * 3 * 4);
    float* xyz2 = (float*)A((size_t)2 * 512 * 3 * 4);
    float* xyz3 = (float*)A((size_t)2 * 128 * 3 * 4);
    float* xyz4 = (float*)A((size_t)2 * 64 * 3 * 4);
    unsigned short* f0 = (unsigned short*)A((size_t)2 * 8192 * 32 * 2);
    unsigned short* f1 = (unsigned short*)A((size_t)2 * 2048 * 64 * 2);
    unsigned short* f2 = (unsigned short*)A((size_t)2 * 512 * 128 * 2);
    unsigned short* f3 = (unsigned short*)A((size_t)2 * 128 * 192 * 2);
    unsigned short* f4 = (unsigned short*)A((size_t)2 * 64 * 192 * 2);

    k_init<<<(2 * 8192 + 255) / 256, 256, 0, stream>>>(pc, feat, w0, b0v, xyz, f0);

    // ---- down path (ws only)
    k_fps<8192, 2048, 512><<<2, 512, 0, stream>>>(xyz, idx1);
    k_gather<<<16, 256, 0, stream>>>(xyz, idx1, xyz1, 8192, 2048);
    k_setconv<8192, 32, 32, 64><<<dim3(2048, 2), 128, 0, stream>>>(
        xyz, f0, xyz1, sc1w1, sc1b1, sc1w2, sc1b2, f1, 0.25f, 2048);

    k_fps<2048, 512, 512><<<2, 512, 0, stream>>>(xyz1, idx2);
    k_gather<<<4, 256, 0, stream>>>(xyz1, idx2, xyz2, 2048, 512);
    k_setconv<2048, 64, 64, 128><<<dim3(512, 2), 128, 0, stream>>>(
        xyz1, f1, xyz2, sc2w1, sc2b1, sc2w2, sc2b2, f2, 1.0f, 512);

    k_fps<512, 128, 256><<<2, 256, 0, stream>>>(xyz2, idx3);
    k_gather<<<1, 256, 0, stream>>>(xyz2, idx3, xyz3, 512, 128);
    k_setconv<512, 128, 128, 192><<<dim3(128, 2), 128, 0, stream>>>(
        xyz2, f2, xyz3, sc3w1, sc3b1, sc3w2, sc3b2, f3, 4.0f, 128);

    k_fps<128, 64, 64><<<2, 64, 0, stream>>>(xyz3, idx4);
    k_gather<<<1, 128, 0, stream>>>(xyz3, idx4, xyz4, 128, 64);
    k_setconv<128, 192, 192, 192><<<dim3(64, 2), 128, 0, stream>>>(
        xyz3, f3, xyz4, sc4w1, sc4b1, sc4w2, sc4b2, f4, 16.0f, 64);

    // ---- up path: u-features live ONLY in their final out regions (f32)
    k_upconv<64, 192, 192, 192, 192, false><<<dim3(128, 2), 64, 0, stream>>>(
        xyz4, xyz3, f4, f3, up4w1, up4b1, up4w2, up4b2, out, O_U3, 128);
    k_upconv<128, 192, 128, 128, 128, true><<<dim3(512, 2), 64, 0, stream>>>(
        xyz3, xyz2, out + O_U3, f2, up3w1, up3b1, up3w2, up3b2, out, O_U2, 512);
    k_upconv<512, 128, 64, 64, 64, true><<<dim3(2048, 2), 64, 0, stream>>>(
        xyz2, xyz1, out + O_U2, f1, up2w1, up2b1, up2w2, up2b2, out, O_U1, 2048);
    k_upconv<2048, 64, 32, 32, 32, true><<<dim3(8192, 2), 64, 0, stream>>>(
        xyz1, xyz, out + O_U1, f0, up1w1, up1b1, up1w2, up1b2, out, O_U0, 8192);

    // ---- x/i outputs written last
    k_finalize<<<(5376 + 255) / 256, 256, 0, stream>>>(
        xyz1, xyz2, xyz3, idx1, idx2, idx3, out);
}

// Round 9
// 4902.039 us; speedup vs baseline: 1.0091x; 1.0091x over previous
//
#include <hip/hip_runtime.h>
#include <hip/hip_bf16.h>
#include <cstdint>

#define DEV __device__ __forceinline__

// Exact per-op-rounded squared distance, matching numpy's ((dx^2+dy^2)+dz^2)
// with no FMA contraction. All index decisions (FPS/ball/kNN) depend on this
// being bit-identical to the f32 reference.
DEV float sqdist(float ax, float ay, float az, float bx, float by, float bz) {
    float dx = __fsub_rn(ax, bx), dy = __fsub_rn(ay, by), dz = __fsub_rn(az, bz);
    return __fadd_rn(__fadd_rn(__fmul_rn(dx, dx), __fmul_rn(dy, dy)), __fmul_rn(dz, dz));
}

DEV unsigned short f2bf(float f) {  // RNE f32 -> bf16 (ws feature storage only)
    unsigned int u = __float_as_uint(f);
    u += 0x7fffu + ((u >> 16) & 1u);
    return (unsigned short)(u >> 16);
}

DEV float bf2f(unsigned short u) { return __uint_as_float(((unsigned int)u) << 16); }

// Output offsets (f32 elements) in return order.
enum : int {
    O_X1 = 0, O_X2 = 12288, O_X3 = 15360,
    O_I1 = 16128, O_I2 = 20224, O_I3 = 21248,
    O_U0 = 21504, O_U1 = 545792, O_U2 = 807936, O_U3 = 939008
};

// ---------------------------------------------------------------- init ------
__global__ __launch_bounds__(256) void k_init(const float* __restrict__ pc,
                                              const float* __restrict__ feat,
                                              const float* __restrict__ w0,
                                              const float* __restrict__ b0,
                                              float* __restrict__ xyz,
                                              unsigned short* __restrict__ f0) {
    const int N = 8192;
    int i = blockIdx.x * blockDim.x + threadIdx.x;
    if (i >= 2 * N) return;
    int b = i / N, n = i % N;
    float fx0 = feat[(b * 3 + 0) * N + n];
    float fx1 = feat[(b * 3 + 1) * N + n];
    float fx2 = feat[(b * 3 + 2) * N + n];
    xyz[i * 3 + 0] = pc[(b * 3 + 0) * N + n];
    xyz[i * 3 + 1] = pc[(b * 3 + 1) * N + n];
    xyz[i * 3 + 2] = pc[(b * 3 + 2) * N + n];
#pragma unroll
    for (int o = 0; o < 32; o++) {
        float acc = b0[o];
        acc = fmaf(w0[o * 3 + 0], fx0, acc);
        acc = fmaf(w0[o * 3 + 1], fx1, acc);
        acc = fmaf(w0[o * 3 + 2], fx2, acc);
        f0[(size_t)i * 32 + o] = f2bf(fmaxf(acc, 0.f));
    }
}

// ----------------------------------------------------------------- FPS ------
// One block per batch. Points + dmin in registers; xyz mirrored in LDS so the
// winner's coords are a broadcast LDS read. Per iteration (ONE barrier):
//   fmax tree over P -> eq-scan + min tree (local i) -> packed u64 key
//   (dist_bits<<32 | ~idx) -> 6-round shfl_xor u64-max butterfly (== max
//   dist, min index: numpy first-max) -> per-wave slot write (double-buffered
//   parity) -> barrier -> serial W-slot reduce -> coords from LDS -> dmin
//   update. L1 uses T=1024 (4 waves/SIMD) purely for latency hiding.
template <int N, int M, int T>
__global__ __launch_bounds__(T, 1) void k_fps(const float* __restrict__ xyz,
                                              int* __restrict__ idx_out) {
    constexpr int P = N / T;
    constexpr int W = T / 64;
    int b = blockIdx.x;
    const float* X = xyz + (size_t)b * N * 3;
    int t = threadIdx.x;
    int w = t >> 6;
    __shared__ float sx[N], sy[N], sz[N];
    __shared__ unsigned long long skey[2][W];
    float px[P], py[P], pz[P], dmin[P];
    float c0x = X[0], c0y = X[1], c0z = X[2];
#pragma unroll
    for (int i = 0; i < P; i++) {
        int p = i * T + t;
        px[i] = X[p * 3 + 0];
        py[i] = X[p * 3 + 1];
        pz[i] = X[p * 3 + 2];
        sx[p] = px[i]; sy[p] = py[i]; sz[p] = pz[i];
        dmin[i] = sqdist(px[i], py[i], pz[i], c0x, c0y, c0z);
    }
    if (t == 0) idx_out[b * M] = 0;
    for (int j = 1; j < M; j++) {
        // local max value: explicit tree (independent ops, depth log2 P)
        float mv[P];
#pragma unroll
        for (int i = 0; i < P; i++) mv[i] = dmin[i];
#pragma unroll
        for (int s = P / 2; s >= 1; s >>= 1)
#pragma unroll
            for (int i = 0; i < s; i++) mv[i] = fmaxf(mv[i], mv[i + s]);
        float bv = mv[0];
        // first (=min) local slot achieving bv -> global index i*T + t
        int ii[P];
#pragma unroll
        for (int i = 0; i < P; i++) ii[i] = (dmin[i] == bv) ? i : 0x7fffffff;
#pragma unroll
        for (int s = P / 2; s >= 1; s >>= 1)
#pragma unroll
            for (int i = 0; i < s; i++) ii[i] = min(ii[i], ii[i + s]);
        int bi = (ii[0] == 0x7fffffff) ? 0x7fffffff : ii[0] * T + t;
        unsigned long long key =
            ((unsigned long long)__float_as_uint(bv) << 32) | (unsigned int)~bi;
#pragma unroll
        for (int m = 1; m < 64; m <<= 1) {
            unsigned long long ok = __shfl_xor(key, m, 64);
            key = ok > key ? ok : key;
        }
        int sl = j & 1;
        if ((t & 63) == 0) skey[sl][w] = key;
        __syncthreads();
        unsigned long long gk = skey[sl][0];
#pragma unroll
        for (int u = 1; u < W; u++) {
            unsigned long long ok = skey[sl][u];
            gk = ok > gk ? ok : gk;
        }
        int gi = (int)~(unsigned int)gk;
        if (t == 0) idx_out[b * M + j] = gi;
        float cx = sx[gi], cy = sy[gi], cz = sz[gi];  // broadcast, conflict-free
#pragma unroll
        for (int i = 0; i < P; i++)
            dmin[i] = fminf(dmin[i], sqdist(px[i], py[i], pz[i], cx, cy, cz));
        // no second barrier: iteration j+1 writes the OTHER slot parity;
        // reaching that write implies passing barrier j, which implies every
        // thread finished reading slot parity j-1 (== j+1's parity).
    }
}

// -------------------------------------------------------------- gather ------
__global__ __launch_bounds__(256) void k_gather(const float* __restrict__ xyz_src,
                                                const int* __restrict__ idx,
                                                float* __restrict__ xyz_dst,
                                                int NS, int M) {
    int i = blockIdx.x * blockDim.x + threadIdx.x;
    if (i >= 2 * M) return;
    int b = i / M;
    int id = idx[i] & (NS - 1);
    xyz_dst[i * 3 + 0] = xyz_src[((size_t)b * NS + id) * 3 + 0];
    xyz_dst[i * 3 + 1] = xyz_src[((size_t)b * NS + id) * 3 + 1];
    xyz_dst[i * 3 + 2] = xyz_src[((size_t)b * NS + id) * 3 + 2];
}

// ------------------------------------------------------------- SetConv ------
template <int NS, int CF, int CMID, int COUT>
__global__ __launch_bounds__(128) void k_setconv(
    const float* __restrict__ X, const unsigned short* __restrict__ F,
    const float* __restrict__ C, const float* __restrict__ w1,
    const float* __restrict__ b1, const float* __restrict__ w2,
    const float* __restrict__ b2, unsigned short* __restrict__ fout,
    float r2, int M) {
    constexpr int CIN = 3 + CF;
    constexpr int K = 16;
    constexpr int M8 = CMID / 8;
    constexpr int O8 = COUT / 8;
    int q = blockIdx.x, b = blockIdx.y;
    int blk = b * M + q;
    const float* Xb = X + (size_t)b * NS * 3;
    const unsigned short* Fb = F + (size_t)b * NS * CF;
    int tid = threadIdx.x;
    __shared__ int s_n[K];
    __shared__ int s_cnt;
    __shared__ float s_h[K][CIN];
    __shared__ float s_mid[K][CMID];
    __shared__ float s_pool[2][COUT];
    float cx = C[(size_t)blk * 3 + 0], cy = C[(size_t)blk * 3 + 1], cz = C[(size_t)blk * 3 + 2];
    if (tid < 64) {
        int lane = tid;
        int cnt = 0;
        for (int base = 0; base < NS; base += 64) {
            int p = base + lane;
            float d2 = sqdist(Xb[p * 3], Xb[p * 3 + 1], Xb[p * 3 + 2], cx, cy, cz);
            bool in = (d2 <= r2);
            unsigned long long msk = __ballot(in);
            if (in) {
                int pos = cnt + __popcll(msk & ((1ull << lane) - 1ull));
                if (pos < K) s_n[pos] = p;
            }
            cnt += __popcll(msk);
            if (cnt >= K) break;
        }
        if (lane == 0) s_cnt = cnt < K ? cnt : K;
    }
    __syncthreads();
    int cnt = s_cnt;
    if (tid >= cnt && tid < K) s_n[tid] = s_n[0];  // pad (center itself always hits)
    __syncthreads();
    for (int tIdx = tid; tIdx < K * CIN; tIdx += 128) {
        int n = tIdx / CIN, c = tIdx % CIN;
        int gi = s_n[n];
        float v;
        if (c < 3) v = __fsub_rn(Xb[gi * 3 + c], (c == 0 ? cx : (c == 1 ? cy : cz)));
        else v = bf2f(Fb[(size_t)gi * CF + (c - 3)]);
        s_h[n][c] = v;
    }
    __syncthreads();
    int n = tid >> 3, sub = tid & 7;
#pragma unroll
    for (int j = 0; j < M8; j++) {
        int m = sub * M8 + j;
        float acc = b1[m];
#pragma unroll 4
        for (int c = 0; c < CIN; c++) acc = fmaf(w1[m * CIN + c], s_h[n][c], acc);
        s_mid[n][m] = fmaxf(acc, 0.f);
    }
    __syncthreads();
    float vals[O8];
#pragma unroll
    for (int j = 0; j < O8; j++) {
        int o = sub * O8 + j;
        float acc = b2[o];
#pragma unroll 4
        for (int c = 0; c < CMID; c++) acc = fmaf(w2[o * CMID + c], s_mid[n][c], acc);
        vals[j] = fmaxf(acc, 0.f);
    }
#pragma unroll
    for (int j = 0; j < O8; j++) {
        vals[j] = fmaxf(vals[j], __shfl_xor(vals[j], 8, 64));
        vals[j] = fmaxf(vals[j], __shfl_xor(vals[j], 16, 64));
        vals[j] = fmaxf(vals[j], __shfl_xor(vals[j], 32, 64));
    }
    int lw = tid & 63, wv = tid >> 6;
    if (lw < 8) {
#pragma unroll
        for (int j = 0; j < O8; j++) s_pool[wv][lw * O8 + j] = vals[j];
    }
    __syncthreads();
    if (tid < 8) {
#pragma unroll
        for (int j = 0; j < O8; j++) {
            int o = tid * O8 + j;
            fout[(size_t)blk * COUT + o] = f2bf(fmaxf(s_pool[0][o], s_pool[1][o]));
        }
    }
}

// ------------------------------------------------------------ SetUpConv -----
template <int S, int CS, int CMID, int CD, int COUT, bool TRANS>
__global__ __launch_bounds__(64) void k_upconv(
    const float* __restrict__ SX, const float* __restrict__ DX,
    const void* __restrict__ SFv, const unsigned short* __restrict__ DF,
    const float* __restrict__ w1, const float* __restrict__ b1,
    const float* __restrict__ w2, const float* __restrict__ b2,
    float* __restrict__ out, int o_off, int ND) {
    constexpr int K = 8;
    constexpr int CIN = 3 + CS;
    constexpr int CIN2 = CMID + CD;
    constexpr int M8 = CMID / 8;
    int q = blockIdx.x, b = blockIdx.y;
    int blk = b * ND + q;
    int lane = threadIdx.x;
    const float* SXb = SX + (size_t)b * S * 3;
    float qx = DX[(size_t)blk * 3], qy = DX[(size_t)blk * 3 + 1], qz = DX[(size_t)blk * 3 + 2];
    __shared__ int s_k[K];
    __shared__ float s_h[K][CIN];
    __shared__ float s_in2[CIN2];
    float bd[K];
    int bi[K];
#pragma unroll
    for (int i = 0; i < K; i++) { bd[i] = 3.0e38f; bi[i] = 0x7fffffff; }
    for (int p = lane; p < S; p += 64) {
        float d2 = sqdist(SXb[p * 3], SXb[p * 3 + 1], SXb[p * 3 + 2], qx, qy, qz);
        if (d2 < bd[K - 1] || (d2 == bd[K - 1] && p < bi[K - 1])) {
            bd[K - 1] = d2; bi[K - 1] = p;
#pragma unroll
            for (int j = K - 1; j > 0; j--) {
                bool sw = (bd[j] < bd[j - 1]) || (bd[j] == bd[j - 1] && bi[j] < bi[j - 1]);
                if (sw) {
                    float tv = bd[j]; bd[j] = bd[j - 1]; bd[j - 1] = tv;
                    int ti = bi[j]; bi[j] = bi[j - 1]; bi[j - 1] = ti;
                }
            }
        }
    }
    for (int r = 0; r < K; r++) {
        float vv = bd[0]; int vi = bi[0];
#pragma unroll
        for (int m = 1; m < 64; m <<= 1) {
            float ov = __shfl_xor(vv, m, 64);
            int oi = __shfl_xor(vi, m, 64);
            if (ov < vv || (ov == vv && oi < vi)) { vv = ov; vi = oi; }
        }
        if (lane == 0) s_k[r] = vi;
        if (vi == bi[0]) {  // unique owner lane pops its head
#pragma unroll
            for (int j = 0; j < K - 1; j++) { bd[j] = bd[j + 1]; bi[j] = bi[j + 1]; }
            bd[K - 1] = 3.0e38f; bi[K - 1] = 0x7fffffff;
        }
    }
    __syncthreads();
    for (int tIdx = lane; tIdx < K * CIN; tIdx += 64) {
        int n = tIdx / CIN, c = tIdx % CIN;
        int gi = s_k[n];
        float v;
        if (c < 3) v = __fsub_rn(SXb[gi * 3 + c], (c == 0 ? qx : (c == 1 ? qy : qz)));
        else if (TRANS) v = ((const float*)SFv)[((size_t)b * CS + (c - 3)) * S + gi];
        else v = bf2f(((const unsigned short*)SFv)[((size_t)b * S + gi) * CS + (c - 3)]);
        s_h[n][c] = v;
    }
    for (int c = lane; c < CD; c += 64) s_in2[CMID + c] = bf2f(DF[(size_t)blk * CD + c]);
    __syncthreads();
    int n = lane >> 3, sub = lane & 7;
    float vals[M8];
#pragma unroll
    for (int j = 0; j < M8; j++) {
        int m = sub * M8 + j;
        float acc = b1[m];
#pragma unroll 4
        for (int c = 0; c < CIN; c++) acc = fmaf(w1[m * CIN + c], s_h[n][c], acc);
        vals[j] = fmaxf(acc, 0.f);
    }
#pragma unroll
    for (int j = 0; j < M8; j++) {
        vals[j] = fmaxf(vals[j], __shfl_xor(vals[j], 8, 64));
        vals[j] = fmaxf(vals[j], __shfl_xor(vals[j], 16, 64));
        vals[j] = fmaxf(vals[j], __shfl_xor(vals[j], 32, 64));
    }
    if (lane < 8) {
#pragma unroll
        for (int j = 0; j < M8; j++) s_in2[lane * M8 + j] = vals[j];
    }
    __syncthreads();
    for (int o = lane; o < COUT; o += 64) {
        float acc = b2[o];
#pragma unroll 4
        for (int c = 0; c < CIN2; c++) acc = fmaf(w2[o * CIN2 + c], s_in2[c], acc);
        out[o_off + ((size_t)b * COUT + o) * ND + q] = fmaxf(acc, 0.f);
    }
}

// ------------------------------------------------------------- finalize -----
__global__ __launch_bounds__(256) void k_finalize(
    const float* __restrict__ xyz1, const float* __restrict__ xyz2,
    const float* __restrict__ xyz3, const int* __restrict__ idx1,
    const int* __restrict__ idx2, const int* __restrict__ idx3,
    float* __restrict__ out) {
    int i = blockIdx.x * blockDim.x + threadIdx.x;
    const float* xs;
    const int* is;
    int M, ox, oi, j;
    if (i < 4096) { xs = xyz1; is = idx1; M = 2048; ox = O_X1; oi = O_I1; j = i; }
    else if (i < 5120) { xs = xyz2; is = idx2; M = 512; ox = O_X2; oi = O_I2; j = i - 4096; }
    else if (i < 5376) { xs = xyz3; is = idx3; M = 128; ox = O_X3; oi = O_I3; j = i - 5120; }
    else return;
    int b = j / M, m = j % M;
    out[ox + (b * 3 + 0) * M + m] = xs[j * 3 + 0];
    out[ox + (b * 3 + 1) * M + m] = xs[j * 3 + 1];
    out[ox + (b * 3 + 2) * M + m] = xs[j * 3 + 2];
    out[oi + j] = (float)is[j];
}

// ---------------------------------------------------------------- launch ----
extern "C" void kernel_launch(void* const* d_in, const int* in_sizes, int n_in,
                              void* d_out, int out_size, void* d_ws, size_t ws_size,
                              hipStream_t stream) {
    const float* pc = (const float*)d_in[0];
    const float* feat = (const float*)d_in[1];
    const float* w0 = (const float*)d_in[2];
    const float* b0v = (const float*)d_in[3];
    const float* sc1w1 = (const float*)d_in[4];  const float* sc1b1 = (const float*)d_in[5];
    const float* sc1w2 = (const float*)d_in[6];  const float* sc1b2 = (const float*)d_in[7];
    const float* sc2w1 = (const float*)d_in[8];  const float* sc2b1 = (const float*)d_in[9];
    const float* sc2w2 = (const float*)d_in[10]; const float* sc2b2 = (const float*)d_in[11];
    const float* sc3w1 = (const float*)d_in[12]; const float* sc3b1 = (const float*)d_in[13];
    const float* sc3w2 = (const float*)d_in[14]; const float* sc3b2 = (const float*)d_in[15];
    const float* sc4w1 = (const float*)d_in[16]; const float* sc4b1 = (const float*)d_in[17];
    const float* sc4w2 = (const float*)d_in[18]; const float* sc4b2 = (const float*)d_in[19];
    const float* up4w1 = (const float*)d_in[20]; const float* up4b1 = (const float*)d_in[21];
    const float* up4w2 = (const float*)d_in[22]; const float* up4b2 = (const float*)d_in[23];
    const float* up3w1 = (const float*)d_in[24]; const float* up3b1 = (const float*)d_in[25];
    const float* up3w2 = (const float*)d_in[26]; const float* up3b2 = (const float*)d_in[27];
    const float* up2w1 = (const float*)d_in[28]; const float* up2b1 = (const float*)d_in[29];
    const float* up2w2 = (const float*)d_in[30]; const float* up2b2 = (const float*)d_in[31];
    const float* up1w1 = (const float*)d_in[32]; const float* up1b1 = (const float*)d_in[33];
    const float* up1w2 = (const float*)d_in[34]; const float* up1b2 = (const float*)d_in[35];
    float* out = (float*)d_out;

    char* ws = (char*)d_ws;
    size_t off = 0;
    auto A = [&](size_t bytes) -> char* {
        char* p = ws + off;
        off += (bytes + 255) & ~(size_t)255;
        return p;
    };
    float* xyz  = (float*)A((size_t)2 * 8192 * 3 * 4);
    int* idx1   = (int*)A((size_t)2 * 2048 * 4);
    int* idx2   = (int*)A((size_t)2 * 512 * 4);
    int* idx3   = (int*)A((size_t)2 * 128 * 4);
    int* idx4   = (int*)A((size_t)2 * 64 * 4);
    float* xyz1 = (float*)A((size_t)2 * 2048 * 3 * 4);
    float* xyz2 = (float*)A((size_t)2 * 512 * 3 * 4);
    float* xyz3 = (float*)A((size_t)2 * 128 * 3 * 4);
    float* xyz4 = (float*)A((size_t)2 * 64 * 3 * 4);
    unsigned short* f0 = (unsigned short*)A((size_t)2 * 8192 * 32 * 2);
    unsigned short* f1 = (unsigned short*)A((size_t)2 * 2048 * 64 * 2);
    unsigned short* f2 = (unsigned short*)A((size_t)2 * 512 * 128 * 2);
    unsigned short* f3 = (unsigned short*)A((size_t)2 * 128 * 192 * 2);
    unsigned short* f4 = (unsigned short*)A((size_t)2 * 64 * 192 * 2);

    k_init<<<(2 * 8192 + 255) / 256, 256, 0, stream>>>(pc, feat, w0, b0v, xyz, f0);

    // ---- down path (ws only)
    k_fps<8192, 2048, 1024><<<2, 1024, 0, stream>>>(xyz, idx1);
    k_gather<<<16, 256, 0, stream>>>(xyz, idx1, xyz1, 8192, 2048);
    k_setconv<8192, 32, 32, 64><<<dim3(2048, 2), 128, 0, stream>>>(
        xyz, f0, xyz1, sc1w1, sc1b1, sc1w2, sc1b2, f1, 0.25f, 2048);

    k_fps<2048, 512, 512><<<2, 512, 0, stream>>>(xyz1, idx2);
    k_gather<<<4, 256, 0, stream>>>(xyz1, idx2, xyz2, 2048, 512);
    k_setconv<2048, 64, 64, 128><<<dim3(512, 2), 128, 0, stream>>>(
        xyz1, f1, xyz2, sc2w1, sc2b1, sc2w2, sc2b2, f2, 1.0f, 512);

    k_fps<512, 128, 256><<<2, 256, 0, stream>>>(xyz2, idx3);
    k_gather<<<1, 256, 0, stream>>>(xyz2, idx3, xyz3, 512, 128);
    k_setconv<512, 128, 128, 192><<<dim3(128, 2), 128, 0, stream>>>(
        xyz2, f2, xyz3, sc3w1, sc3b1, sc3w2, sc3b2, f3, 4.0f, 128);

    k_fps<128, 64, 128><<<2, 128, 0, stream>>>(xyz3, idx4);
    k_gather<<<1, 128, 0, stream>>>(xyz3, idx4, xyz4, 128, 64);
    k_setconv<128, 192, 192, 192><<<dim3(64, 2), 128, 0, stream>>>(
        xyz3, f3, xyz4, sc4w1, sc4b1, sc4w2, sc4b2, f4, 16.0f, 64);

    // ---- up path: u-features live ONLY in their final out regions (f32)
    k_upconv<64, 192, 192, 192, 192, false><<<dim3(128, 2), 64, 0, stream>>>(
        xyz4, xyz3, f4, f3, up4w1, up4b1, up4w2, up4b2, out, O_U3, 128);
    k_upconv<128, 192, 128, 128, 128, true><<<dim3(512, 2), 64, 0, stream>>>(
        xyz3, xyz2, out + O_U3, f2, up3w1, up3b1, up3w2, up3b2, out, O_U2, 512);
    k_upconv<512, 128, 64, 64, 64, true><<<dim3(2048, 2), 64, 0, stream>>>(
        xyz2, xyz1, out + O_U2, f1, up2w1, up2b1, up2w2, up2b2, out, O_U1, 2048);
    k_upconv<2048, 64, 32, 32, 32, true><<<dim3(8192, 2), 64, 0, stream>>>(
        xyz1, xyz, out + O_U1, f0, up1w1, up1b1, up1w2, up1b2, out, O_U0, 8192);

    // ---- x/i outputs written last
    k_finalize<<<(5376 + 255) / 256, 256, 0, stream>>>(
        xyz1, xyz2, xyz3, idx1, idx2, idx3, out);
}

// Round 10
// 4557.100 us; speedup vs baseline: 1.0855x; 1.0757x over previous
//
#include <hip/hip_runtime.h>
#include <hip/hip_bf16.h>
#include <cstdint>

#define DEV __device__ __forceinline__

typedef float f32x2 __attribute__((ext_vector_type(2)));

// Exact per-op-rounded squared distance, matching numpy's ((dx^2+dy^2)+dz^2)
// with no FMA contraction. All index decisions (FPS/ball/kNN) depend on this
// being bit-identical to the f32 reference.
DEV float sqdist(float ax, float ay, float az, float bx, float by, float bz) {
    float dx = __fsub_rn(ax, bx), dy = __fsub_rn(ay, by), dz = __fsub_rn(az, bz);
    return __fadd_rn(__fadd_rn(__fmul_rn(dx, dx), __fmul_rn(dy, dy)), __fmul_rn(dz, dz));
}

// Vector (pairwise) version: element-wise IEEE rn sub/mul/add with contraction
// OFF == bit-identical to the scalar chain, but packs into v_pk_* ops.
DEV f32x2 sqdist2(f32x2 ax, f32x2 ay, f32x2 az, float bx, float by, float bz) {
#pragma clang fp contract(off)
    f32x2 dx = ax - bx, dy = ay - by, dz = az - bz;
    return (dx * dx + dy * dy) + dz * dz;
}

DEV unsigned short f2bf(float f) {  // RNE f32 -> bf16 (ws feature storage only)
    unsigned int u = __float_as_uint(f);
    u += 0x7fffu + ((u >> 16) & 1u);
    return (unsigned short)(u >> 16);
}

DEV float bf2f(unsigned short u) { return __uint_as_float(((unsigned int)u) << 16); }

// Output offsets (f32 elements) in return order.
enum : int {
    O_X1 = 0, O_X2 = 12288, O_X3 = 15360,
    O_I1 = 16128, O_I2 = 20224, O_I3 = 21248,
    O_U0 = 21504, O_U1 = 545792, O_U2 = 807936, O_U3 = 939008
};

// ---------------------------------------------------------------- init ------
__global__ __launch_bounds__(256) void k_init(const float* __restrict__ pc,
                                              const float* __restrict__ feat,
                                              const float* __restrict__ w0,
                                              const float* __restrict__ b0,
                                              float* __restrict__ xyz,
                                              unsigned short* __restrict__ f0) {
    const int N = 8192;
    int i = blockIdx.x * blockDim.x + threadIdx.x;
    if (i >= 2 * N) return;
    int b = i / N, n = i % N;
    float fx0 = feat[(b * 3 + 0) * N + n];
    float fx1 = feat[(b * 3 + 1) * N + n];
    float fx2 = feat[(b * 3 + 2) * N + n];
    xyz[i * 3 + 0] = pc[(b * 3 + 0) * N + n];
    xyz[i * 3 + 1] = pc[(b * 3 + 1) * N + n];
    xyz[i * 3 + 2] = pc[(b * 3 + 2) * N + n];
#pragma unroll
    for (int o = 0; o < 32; o++) {
        float acc = b0[o];
        acc = fmaf(w0[o * 3 + 0], fx0, acc);
        acc = fmaf(w0[o * 3 + 1], fx1, acc);
        acc = fmaf(w0[o * 3 + 2], fx2, acc);
        f0[(size_t)i * 32 + o] = f2bf(fmaxf(acc, 0.f));
    }
}

// ----------------------------------------------------------------- FPS ------
// One block per batch, T=512 (2 waves/SIMD — measured optimum). Points+dmin
// in PAIRED registers (f32x2 -> v_pk_* update); xyz mirrored in LDS so the
// winner's coords are a broadcast LDS read. Per iteration (ONE barrier):
//   vector fmax tree -> eq-scan + min tree (first-max index) -> packed u64
//   key (dist_bits<<32 | ~idx) -> 6-round shfl_xor u64-max butterfly ->
//   per-wave lane0 LDS atomicMax into ONE slot (triple-buffered, reset one
//   iteration later) -> barrier -> broadcast slot read -> coords from LDS ->
//   packed dmin update. Key order == numpy first-max (max dist, min index).
template <int N, int M, int T>
__global__ __launch_bounds__(T, 1) void k_fps(const float* __restrict__ xyz,
                                              int* __restrict__ idx_out) {
    constexpr int P = N / T;
    constexpr int P2 = P / 2;
    constexpr int W = T / 64;
    int b = blockIdx.x;
    const float* X = xyz + (size_t)b * N * 3;
    int t = threadIdx.x;
    __shared__ float sx[N], sy[N], sz[N];
    __shared__ unsigned long long skey[3];
    f32x2 px[P2], py[P2], pz[P2], dmin[P2];
    float c0x = X[0], c0y = X[1], c0z = X[2];
#pragma unroll
    for (int i = 0; i < P2; i++) {
        int p0 = (2 * i) * T + t, p1 = (2 * i + 1) * T + t;
        px[i] = f32x2{X[p0 * 3 + 0], X[p1 * 3 + 0]};
        py[i] = f32x2{X[p0 * 3 + 1], X[p1 * 3 + 1]};
        pz[i] = f32x2{X[p0 * 3 + 2], X[p1 * 3 + 2]};
        sx[p0] = px[i].x; sy[p0] = py[i].x; sz[p0] = pz[i].x;
        sx[p1] = px[i].y; sy[p1] = py[i].y; sz[p1] = pz[i].y;
        dmin[i] = sqdist2(px[i], py[i], pz[i], c0x, c0y, c0z);
    }
    if (t == 0) {
        idx_out[b * M] = 0;
        skey[0] = 0; skey[1] = 0; skey[2] = 0;
    }
    __syncthreads();
    int jm = 1;  // j % 3, maintained incrementally
    for (int j = 1; j < M; j++) {
        // local max value: vector tree then scalar combine
        f32x2 m2[P2];
#pragma unroll
        for (int i = 0; i < P2; i++) m2[i] = dmin[i];
#pragma unroll
        for (int s = P2 / 2; s >= 1; s >>= 1)
#pragma unroll
            for (int i = 0; i < s; i++) m2[i] = __builtin_elementwise_max(m2[i], m2[i + s]);
        float bv = fmaxf(m2[0].x, m2[0].y);
        // first (=min) global index achieving bv: eq-scan + min tree
        int ii[P];
#pragma unroll
        for (int i = 0; i < P; i++)
            ii[i] = (dmin[i >> 1][i & 1] == bv) ? (i * T + t) : 0x7fffffff;
#pragma unroll
        for (int s = P / 2; s >= 1; s >>= 1)
#pragma unroll
            for (int i = 0; i < s; i++) ii[i] = min(ii[i], ii[i + s]);
        int bi = ii[0];
        unsigned long long key =
            ((unsigned long long)__float_as_uint(bv) << 32) | (unsigned int)~bi;
#pragma unroll
        for (int m = 1; m < 64; m <<= 1) {
            unsigned long long ok = __shfl_xor(key, m, 64);
            key = ok > key ? ok : key;
        }
        int gi;
        if constexpr (W > 1) {
            if ((t & 63) == 0) atomicMax(&skey[jm], key);
            __syncthreads();
            unsigned long long gk = skey[jm];
            gi = (int)~(unsigned int)gk;
            // reset the PREVIOUS slot: its readers all passed the barrier we
            // just crossed; its next atomic use is 2 iterations away (after
            // the NEXT barrier), so a plain store here is race-free.
            if (t == 0) skey[jm == 0 ? 2 : jm - 1] = 0;
            jm = (jm == 2) ? 0 : jm + 1;
        } else {
            gi = bi;
        }
        if (t == 0) idx_out[b * M + j] = gi;
        float cx = sx[gi], cy = sy[gi], cz = sz[gi];  // broadcast, conflict-free
#pragma unroll
        for (int i = 0; i < P2; i++)
            dmin[i] = __builtin_elementwise_min(
                dmin[i], sqdist2(px[i], py[i], pz[i], cx, cy, cz));
    }
}

// -------------------------------------------------------------- gather ------
__global__ __launch_bounds__(256) void k_gather(const float* __restrict__ xyz_src,
                                                const int* __restrict__ idx,
                                                float* __restrict__ xyz_dst,
                                                int NS, int M) {
    int i = blockIdx.x * blockDim.x + threadIdx.x;
    if (i >= 2 * M) return;
    int b = i / M;
    int id = idx[i] & (NS - 1);
    xyz_dst[i * 3 + 0] = xyz_src[((size_t)b * NS + id) * 3 + 0];
    xyz_dst[i * 3 + 1] = xyz_src[((size_t)b * NS + id) * 3 + 1];
    xyz_dst[i * 3 + 2] = xyz_src[((size_t)b * NS + id) * 3 + 2];
}

// ------------------------------------------------------------- SetConv ------
template <int NS, int CF, int CMID, int COUT>
__global__ __launch_bounds__(128) void k_setconv(
    const float* __restrict__ X, const unsigned short* __restrict__ F,
    const float* __restrict__ C, const float* __restrict__ w1,
    const float* __restrict__ b1, const float* __restrict__ w2,
    const float* __restrict__ b2, unsigned short* __restrict__ fout,
    float r2, int M) {
    constexpr int CIN = 3 + CF;
    constexpr int K = 16;
    constexpr int M8 = CMID / 8;
    constexpr int O8 = COUT / 8;
    int q = blockIdx.x, b = blockIdx.y;
    int blk = b * M + q;
    const float* Xb = X + (size_t)b * NS * 3;
    const unsigned short* Fb = F + (size_t)b * NS * CF;
    int tid = threadIdx.x;
    __shared__ int s_n[K];
    __shared__ int s_cnt;
    __shared__ float s_h[K][CIN];
    __shared__ float s_mid[K][CMID];
    __shared__ float s_pool[2][COUT];
    float cx = C[(size_t)blk * 3 + 0], cy = C[(size_t)blk * 3 + 1], cz = C[(size_t)blk * 3 + 2];
    if (tid < 64) {
        int lane = tid;
        int cnt = 0;
        for (int base = 0; base < NS; base += 64) {
            int p = base + lane;
            float d2 = sqdist(Xb[p * 3], Xb[p * 3 + 1], Xb[p * 3 + 2], cx, cy, cz);
            bool in = (d2 <= r2);
            unsigned long long msk = __ballot(in);
            if (in) {
                int pos = cnt + __popcll(msk & ((1ull << lane) - 1ull));
                if (pos < K) s_n[pos] = p;
            }
            cnt += __popcll(msk);
            if (cnt >= K) break;
        }
        if (lane == 0) s_cnt = cnt < K ? cnt : K;
    }
    __syncthreads();
    int cnt = s_cnt;
    if (tid >= cnt && tid < K) s_n[tid] = s_n[0];  // pad (center itself always hits)
    __syncthreads();
    for (int tIdx = tid; tIdx < K * CIN; tIdx += 128) {
        int n = tIdx / CIN, c = tIdx % CIN;
        int gi = s_n[n];
        float v;
        if (c < 3) v = __fsub_rn(Xb[gi * 3 + c], (c == 0 ? cx : (c == 1 ? cy : cz)));
        else v = bf2f(Fb[(size_t)gi * CF + (c - 3)]);
        s_h[n][c] = v;
    }
    __syncthreads();
    int n = tid >> 3, sub = tid & 7;
#pragma unroll
    for (int j = 0; j < M8; j++) {
        int m = sub * M8 + j;
        float acc = b1[m];
#pragma unroll 4
        for (int c = 0; c < CIN; c++) acc = fmaf(w1[m * CIN + c], s_h[n][c], acc);
        s_mid[n][m] = fmaxf(acc, 0.f);
    }
    __syncthreads();
    float vals[O8];
#pragma unroll
    for (int j = 0; j < O8; j++) {
        int o = sub * O8 + j;
        float acc = b2[o];
#pragma unroll 4
        for (int c = 0; c < CMID; c++) acc = fmaf(w2[o * CMID + c], s_mid[n][c], acc);
        vals[j] = fmaxf(acc, 0.f);
    }
#pragma unroll
    for (int j = 0; j < O8; j++) {
        vals[j] = fmaxf(vals[j], __shfl_xor(vals[j], 8, 64));
        vals[j] = fmaxf(vals[j], __shfl_xor(vals[j], 16, 64));
        vals[j] = fmaxf(vals[j], __shfl_xor(vals[j], 32, 64));
    }
    int lw = tid & 63, wv = tid >> 6;
    if (lw < 8) {
#pragma unroll
        for (int j = 0; j < O8; j++) s_pool[wv][lw * O8 + j] = vals[j];
    }
    __syncthreads();
    if (tid < 8) {
#pragma unroll
        for (int j = 0; j < O8; j++) {
            int o = tid * O8 + j;
            fout[(size_t)blk * COUT + o] = f2bf(fmaxf(s_pool[0][o], s_pool[1][o]));
        }
    }
}

// ------------------------------------------------------------ SetUpConv -----
template <int S, int CS, int CMID, int CD, int COUT, bool TRANS>
__global__ __launch_bounds__(64) void k_upconv(
    const float* __restrict__ SX, const float* __restrict__ DX,
    const void* __restrict__ SFv, const unsigned short* __restrict__ DF,
    const float* __restrict__ w1, const float* __restrict__ b1,
    const float* __restrict__ w2, const float* __restrict__ b2,
    float* __restrict__ out, int o_off, int ND) {
    constexpr int K = 8;
    constexpr int CIN = 3 + CS;
    constexpr int CIN2 = CMID + CD;
    constexpr int M8 = CMID / 8;
    int q = blockIdx.x, b = blockIdx.y;
    int blk = b * ND + q;
    int lane = threadIdx.x;
    const float* SXb = SX + (size_t)b * S * 3;
    float qx = DX[(size_t)blk * 3], qy = DX[(size_t)blk * 3 + 1], qz = DX[(size_t)blk * 3 + 2];
    __shared__ int s_k[K];
    __shared__ float s_h[K][CIN];
    __shared__ float s_in2[CIN2];
    float bd[K];
    int bi[K];
#pragma unroll
    for (int i = 0; i < K; i++) { bd[i] = 3.0e38f; bi[i] = 0x7fffffff; }
    for (int p = lane; p < S; p += 64) {
        float d2 = sqdist(SXb[p * 3], SXb[p * 3 + 1], SXb[p * 3 + 2], qx, qy, qz);
        if (d2 < bd[K - 1] || (d2 == bd[K - 1] && p < bi[K - 1])) {
            bd[K - 1] = d2; bi[K - 1] = p;
#pragma unroll
            for (int j = K - 1; j > 0; j--) {
                bool sw = (bd[j] < bd[j - 1]) || (bd[j] == bd[j - 1] && bi[j] < bi[j - 1]);
                if (sw) {
                    float tv = bd[j]; bd[j] = bd[j - 1]; bd[j - 1] = tv;
                    int ti = bi[j]; bi[j] = bi[j - 1]; bi[j - 1] = ti;
                }
            }
        }
    }
    for (int r = 0; r < K; r++) {
        float vv = bd[0]; int vi = bi[0];
#pragma unroll
        for (int m = 1; m < 64; m <<= 1) {
            float ov = __shfl_xor(vv, m, 64);
            int oi = __shfl_xor(vi, m, 64);
            if (ov < vv || (ov == vv && oi < vi)) { vv = ov; vi = oi; }
        }
        if (lane == 0) s_k[r] = vi;
        if (vi == bi[0]) {  // unique owner lane pops its head
#pragma unroll
            for (int j = 0; j < K - 1; j++) { bd[j] = bd[j + 1]; bi[j] = bi[j + 1]; }
            bd[K - 1] = 3.0e38f; bi[K - 1] = 0x7fffffff;
        }
    }
    __syncthreads();
    for (int tIdx = lane; tIdx < K * CIN; tIdx += 64) {
        int n = tIdx / CIN, c = tIdx % CIN;
        int gi = s_k[n];
        float v;
        if (c < 3) v = __fsub_rn(SXb[gi * 3 + c], (c == 0 ? qx : (c == 1 ? qy : qz)));
        else if (TRANS) v = ((const float*)SFv)[((size_t)b * CS + (c - 3)) * S + gi];
        else v = bf2f(((const unsigned short*)SFv)[((size_t)b * S + gi) * CS + (c - 3)]);
        s_h[n][c] = v;
    }
    for (int c = lane; c < CD; c += 64) s_in2[CMID + c] = bf2f(DF[(size_t)blk * CD + c]);
    __syncthreads();
    int n = lane >> 3, sub = lane & 7;
    float vals[M8];
#pragma unroll
    for (int j = 0; j < M8; j++) {
        int m = sub * M8 + j;
        float acc = b1[m];
#pragma unroll 4
        for (int c = 0; c < CIN; c++) acc = fmaf(w1[m * CIN + c], s_h[n][c], acc);
        vals[j] = fmaxf(acc, 0.f);
    }
#pragma unroll
    for (int j = 0; j < M8; j++) {
        vals[j] = fmaxf(vals[j], __shfl_xor(vals[j], 8, 64));
        vals[j] = fmaxf(vals[j], __shfl_xor(vals[j], 16, 64));
        vals[j] = fmaxf(vals[j], __shfl_xor(vals[j], 32, 64));
    }
    if (lane < 8) {
#pragma unroll
        for (int j = 0; j < M8; j++) s_in2[lane * M8 + j] = vals[j];
    }
    __syncthreads();
    for (int o = lane; o < COUT; o += 64) {
        float acc = b2[o];
#pragma unroll 4
        for (int c = 0; c < CIN2; c++) acc = fmaf(w2[o * CIN2 + c], s_in2[c], acc);
        out[o_off + ((size_t)b * COUT + o) * ND + q] = fmaxf(acc, 0.f);
    }
}

// ------------------------------------------------------------- finalize -----
__global__ __launch_bounds__(256) void k_finalize(
    const float* __restrict__ xyz1, const float* __restrict__ xyz2,
    const float* __restrict__ xyz3, const int* __restrict__ idx1,
    const int* __restrict__ idx2, const int* __restrict__ idx3,
    float* __restrict__ out) {
    int i = blockIdx.x * blockDim.x + threadIdx.x;
    const float* xs;
    const int* is;
    int M, ox, oi, j;
    if (i < 4096) { xs = xyz1; is = idx1; M = 2048; ox = O_X1; oi = O_I1; j = i; }
    else if (i < 5120) { xs = xyz2; is = idx2; M = 512; ox = O_X2; oi = O_I2; j = i - 4096; }
    else if (i < 5376) { xs = xyz3; is = idx3; M = 128; ox = O_X3; oi = O_I3; j = i - 5120; }
    else return;
    int b = j / M, m = j % M;
    out[ox + (b * 3 + 0) * M + m] = xs[j * 3 + 0];
    out[ox + (b * 3 + 1) * M + m] = xs[j * 3 + 1];
    out[ox + (b * 3 + 2) * M + m] = xs[j * 3 + 2];
    out[oi + j] = (float)is[j];
}

// ---------------------------------------------------------------- launch ----
extern "C" void kernel_launch(void* const* d_in, const int* in_sizes, int n_in,
                              void* d_out, int out_size, void* d_ws, size_t ws_size,
                              hipStream_t stream) {
    const float* pc = (const float*)d_in[0];
    const float* feat = (const float*)d_in[1];
    const float* w0 = (const float*)d_in[2];
    const float* b0v = (const float*)d_in[3];
    const float* sc1w1 = (const float*)d_in[4];  const float* sc1b1 = (const float*)d_in[5];
    const float* sc1w2 = (const float*)d_in[6];  const float* sc1b2 = (const float*)d_in[7];
    const float* sc2w1 = (const float*)d_in[8];  const float* sc2b1 = (const float*)d_in[9];
    const float* sc2w2 = (const float*)d_in[10]; const float* sc2b2 = (const float*)d_in[11];
    const float* sc3w1 = (const float*)d_in[12]; const float* sc3b1 = (const float*)d_in[13];
    const float* sc3w2 = (const float*)d_in[14]; const float* sc3b2 = (const float*)d_in[15];
    const float* sc4w1 = (const float*)d_in[16]; const float* sc4b1 = (const float*)d_in[17];
    const float* sc4w2 = (const float*)d_in[18]; const float* sc4b2 = (const float*)d_in[19];
    const float* up4w1 = (const float*)d_in[20]; const float* up4b1 = (const float*)d_in[21];
    const float* up4w2 = (const float*)d_in[22]; const float* up4b2 = (const float*)d_in[23];
    const float* up3w1 = (const float*)d_in[24]; const float* up3b1 = (const float*)d_in[25];
    const float* up3w2 = (const float*)d_in[26]; const float* up3b2 = (const float*)d_in[27];
    const float* up2w1 = (const float*)d_in[28]; const float* up2b1 = (const float*)d_in[29];
    const float* up2w2 = (const float*)d_in[30]; const float* up2b2 = (const float*)d_in[31];
    const float* up1w1 = (const float*)d_in[32]; const float* up1b1 = (const float*)d_in[33];
    const float* up1w2 = (const float*)d_in[34]; const float* up1b2 = (const float*)d_in[35];
    float* out = (float*)d_out;

    char* ws = (char*)d_ws;
    size_t off = 0;
    auto A = [&](size_t bytes) -> char* {
        char* p = ws + off;
        off += (bytes + 255) & ~(size_t)255;
        return p;
    };
    float* xyz  = (float*)A((size_t)2 * 8192 * 3 * 4);
    int* idx1   = (int*)A((size_t)2 * 2048 * 4);
    int* idx2   = (int*)A((size_t)2 * 512 * 4);
    int* idx3   = (int*)A((size_t)2 * 128 * 4);
    int* idx4   = (int*)A((size_t)2 * 64 * 4);
    float* xyz1 = (float*)A((size_t)2 * 2048 * 3 * 4);
    float* xyz2 = (float*)A((size_t)2 * 512 * 3 * 4);
    float* xyz3 = (float*)A((size_t)2 * 128 * 3 * 4);
    float* xyz4 = (float*)A((size_t)2 * 64 * 3 * 4);
    unsigned short* f0 = (unsigned short*)A((size_t)2 * 8192 * 32 * 2);
    unsigned short* f1 = (unsigned short*)A((size_t)2 * 2048 * 64 * 2);
    unsigned short* f2 = (unsigned short*)A((size_t)2 * 512 * 128 * 2);
    unsigned short* f3 = (unsigned short*)A((size_t)2 * 128 * 192 * 2);
    unsigned short* f4 = (unsigned short*)A((size_t)2 * 64 * 192 * 2);

    k_init<<<(2 * 8192 + 255) / 256, 256, 0, stream>>>(pc, feat, w0, b0v, xyz, f0);

    // ---- down path (ws only)
    k_fps<8192, 2048, 512><<<2, 512, 0, stream>>>(xyz, idx1);
    k_gather<<<16, 256, 0, stream>>>(xyz, idx1, xyz1, 8192, 2048);
    k_setconv<8192, 32, 32, 64><<<dim3(2048, 2), 128, 0, stream>>>(
        xyz, f0, xyz1, sc1w1, sc1b1, sc1w2, sc1b2, f1, 0.25f, 2048);

    k_fps<2048, 512, 512><<<2, 512, 0, stream>>>(xyz1, idx2);
    k_gather<<<4, 256, 0, stream>>>(xyz1, idx2, xyz2, 2048, 512);
    k_setconv<2048, 64, 64, 128><<<dim3(512, 2), 128, 0, stream>>>(
        xyz1, f1, xyz2, sc2w1, sc2b1, sc2w2, sc2b2, f2, 1.0f, 512);

    k_fps<512, 128, 256><<<2, 256, 0, stream>>>(xyz2, idx3);
    k_gather<<<1, 256, 0, stream>>>(xyz2, idx3, xyz3, 512, 128);
    k_setconv<512, 128, 128, 192><<<dim3(128, 2), 128, 0, stream>>>(
        xyz2, f2, xyz3, sc3w1, sc3b1, sc3w2, sc3b2, f3, 4.0f, 128);

    k_fps<128, 64, 64><<<2, 64, 0, stream>>>(xyz3, idx4);
    k_gather<<<1, 128, 0, stream>>>(xyz3, idx4, xyz4, 128, 64);
    k_setconv<128, 192, 192, 192><<<dim3(64, 2), 128, 0, stream>>>(
        xyz3, f3, xyz4, sc4w1, sc4b1, sc4w2, sc4b2, f4, 16.0f, 64);

    // ---- up path: u-features live ONLY in their final out regions (f32)
    k_upconv<64, 192, 192, 192, 192, false><<<dim3(128, 2), 64, 0, stream>>>(
        xyz4, xyz3, f4, f3, up4w1, up4b1, up4w2, up4b2, out, O_U3, 128);
    k_upconv<128, 192, 128, 128, 128, true><<<dim3(512, 2), 64, 0, stream>>>(
        xyz3, xyz2, out + O_U3, f2, up3w1, up3b1, up3w2, up3b2, out, O_U2, 512);
    k_upconv<512, 128, 64, 64, 64, true><<<dim3(2048, 2), 64, 0, stream>>>(
        xyz2, xyz1, out + O_U2, f1, up2w1, up2b1, up2w2, up2b2, out, O_U1, 2048);
    k_upconv<2048, 64, 32, 32, 32, true><<<dim3(8192, 2), 64, 0, stream>>>(
        xyz1, xyz, out + O_U1, f0, up1w1, up1b1, up1w2, up1b2, out, O_U0, 8192);

    // ---- x/i outputs written last
    k_finalize<<<(5376 + 255) / 256, 256, 0, stream>>>(
        xyz1, xyz2, xyz3, idx1, idx2, idx3, out);
}

// Round 11
// 4046.629 us; speedup vs baseline: 1.2224x; 1.1261x over previous
//
#include <hip/hip_runtime.h>
#include <hip/hip_bf16.h>
#include <cstdint>

#define DEV __device__ __forceinline__

typedef float f32x2 __attribute__((ext_vector_type(2)));

// Exact per-op-rounded squared distance, matching numpy's ((dx^2+dy^2)+dz^2)
// with no FMA contraction. All index decisions (FPS/ball/kNN) depend on this
// being bit-identical to the f32 reference.
DEV float sqdist(float ax, float ay, float az, float bx, float by, float bz) {
    float dx = __fsub_rn(ax, bx), dy = __fsub_rn(ay, by), dz = __fsub_rn(az, bz);
    return __fadd_rn(__fadd_rn(__fmul_rn(dx, dx), __fmul_rn(dy, dy)), __fmul_rn(dz, dz));
}

// Vector (pairwise) version: element-wise IEEE rn sub/mul/add with contraction
// OFF == bit-identical to the scalar chain, but packs into v_pk_* ops.
DEV f32x2 sqdist2(f32x2 ax, f32x2 ay, f32x2 az, float bx, float by, float bz) {
#pragma clang fp contract(off)
    f32x2 dx = ax - bx, dy = ay - by, dz = az - bz;
    return (dx * dx + dy * dy) + dz * dz;
}

DEV unsigned short f2bf(float f) {  // RNE f32 -> bf16 (ws feature storage only)
    unsigned int u = __float_as_uint(f);
    u += 0x7fffu + ((u >> 16) & 1u);
    return (unsigned short)(u >> 16);
}

DEV float bf2f(unsigned short u) { return __uint_as_float(((unsigned int)u) << 16); }

template <int CTRL>
DEV int dpp_i(int v) { return __builtin_amdgcn_update_dpp(v, v, CTRL, 0xf, 0xf, false); }
template <int CTRL>
DEV float dpp_f(float v) { return __int_as_float(dpp_i<CTRL>(__float_as_int(v))); }

// Output offsets (f32 elements) in return order.
enum : int {
    O_X1 = 0, O_X2 = 12288, O_X3 = 15360,
    O_I1 = 16128, O_I2 = 20224, O_I3 = 21248,
    O_U0 = 21504, O_U1 = 545792, O_U2 = 807936, O_U3 = 939008
};

// ---------------------------------------------------------------- init ------
__global__ __launch_bounds__(256) void k_init(const float* __restrict__ pc,
                                              const float* __restrict__ feat,
                                              const float* __restrict__ w0,
                                              const float* __restrict__ b0,
                                              float* __restrict__ xyz,
                                              unsigned short* __restrict__ f0) {
    const int N = 8192;
    int i = blockIdx.x * blockDim.x + threadIdx.x;
    if (i >= 2 * N) return;
    int b = i / N, n = i % N;
    float fx0 = feat[(b * 3 + 0) * N + n];
    float fx1 = feat[(b * 3 + 1) * N + n];
    float fx2 = feat[(b * 3 + 2) * N + n];
    xyz[i * 3 + 0] = pc[(b * 3 + 0) * N + n];
    xyz[i * 3 + 1] = pc[(b * 3 + 1) * N + n];
    xyz[i * 3 + 2] = pc[(b * 3 + 2) * N + n];
#pragma unroll
    for (int o = 0; o < 32; o++) {
        float acc = b0[o];
        acc = fmaf(w0[o * 3 + 0], fx0, acc);
        acc = fmaf(w0[o * 3 + 1], fx1, acc);
        acc = fmaf(w0[o * 3 + 2], fx2, acc);
        f0[(size_t)i * 32 + o] = f2bf(fmaxf(acc, 0.f));
    }
}

// ----------------------------------------------------------------- FPS ------
// One block per batch, T=512 (2 waves/SIMD — measured optimum). Points+dmin
// in paired registers; xyz mirrored in LDS for broadcast coord reads.
// Per iteration (ONE barrier):
//   vector fmax tree -> eq-scan + min tree (first-max local index) ->
//   wave reduce via TWO single-op DPP chains (v_max_f32 then masked
//   v_min_u32; ror1/2/4/8 + row_bcast15 + row_bcast31) -> readlane(63) ->
//   [W>1: lane0 LDS atomicMax of packed u64 key into one triple-buffered
//   slot -> barrier -> broadcast read] -> coords from LDS -> packed update.
//   Key (dist_bits<<32 | ~idx) == numpy first-max (max dist, min index).
template <int N, int M, int T>
__global__ __launch_bounds__(T, 1) void k_fps(const float* __restrict__ xyz,
                                              int* __restrict__ idx_out) {
    constexpr int P = N / T;
    constexpr int P2 = P / 2;
    constexpr int W = T / 64;
    int b = blockIdx.x;
    const float* X = xyz + (size_t)b * N * 3;
    int t = threadIdx.x;
    __shared__ float sx[N], sy[N], sz[N];
    __shared__ unsigned long long skey[3];
    f32x2 px[P2], py[P2], pz[P2], dmin[P2];
    float c0x = X[0], c0y = X[1], c0z = X[2];
#pragma unroll
    for (int i = 0; i < P2; i++) {
        int p0 = (2 * i) * T + t, p1 = (2 * i + 1) * T + t;
        px[i] = f32x2{X[p0 * 3 + 0], X[p1 * 3 + 0]};
        py[i] = f32x2{X[p0 * 3 + 1], X[p1 * 3 + 1]};
        pz[i] = f32x2{X[p0 * 3 + 2], X[p1 * 3 + 2]};
        sx[p0] = px[i].x; sy[p0] = py[i].x; sz[p0] = pz[i].x;
        sx[p1] = px[i].y; sy[p1] = py[i].y; sz[p1] = pz[i].y;
        dmin[i] = sqdist2(px[i], py[i], pz[i], c0x, c0y, c0z);
    }
    if (t == 0) {
        idx_out[b * M] = 0;
        skey[0] = 0; skey[1] = 0; skey[2] = 0;
    }
    __syncthreads();
    int jm = 1;  // j % 3, maintained incrementally
    for (int j = 1; j < M; j++) {
        // local max value: vector tree then scalar combine
        f32x2 m2[P2];
#pragma unroll
        for (int i = 0; i < P2; i++) m2[i] = dmin[i];
#pragma unroll
        for (int s = P2 / 2; s >= 1; s >>= 1)
#pragma unroll
            for (int i = 0; i < s; i++) m2[i] = __builtin_elementwise_max(m2[i], m2[i + s]);
        float bv = fmaxf(m2[0].x, m2[0].y);
        // first (=min) global index achieving bv: eq-scan + min tree
        int ii[P];
#pragma unroll
        for (int i = 0; i < P; i++)
            ii[i] = (dmin[i >> 1][i & 1] == bv) ? (i * T + t) : 0x7fffffff;
#pragma unroll
        for (int s = P / 2; s >= 1; s >>= 1)
#pragma unroll
            for (int i = 0; i < s; i++) ii[i] = min(ii[i], ii[i + s]);
        int bi = ii[0];
        // ---- wave reduce, phase 1: fmax via single-op DPP chain -> lane 63
        float bw = bv;
        bw = fmaxf(bw, dpp_f<0x121>(bw));   // row_ror:1
        bw = fmaxf(bw, dpp_f<0x122>(bw));   // row_ror:2
        bw = fmaxf(bw, dpp_f<0x124>(bw));   // row_ror:4
        bw = fmaxf(bw, dpp_f<0x128>(bw));   // row_ror:8
        bw = fmaxf(bw, dpp_f<0x142>(bw));   // row_bcast:15
        bw = fmaxf(bw, dpp_f<0x143>(bw));   // row_bcast:31
        float bvw = __int_as_float(__builtin_amdgcn_readlane(__float_as_int(bw), 63));
        // ---- phase 2: masked u32 min of candidate indices -> lane 63
        unsigned int im = (bv == bvw) ? (unsigned int)bi : 0xffffffffu;
        im = min(im, (unsigned int)dpp_i<0x121>((int)im));
        im = min(im, (unsigned int)dpp_i<0x122>((int)im));
        im = min(im, (unsigned int)dpp_i<0x124>((int)im));
        im = min(im, (unsigned int)dpp_i<0x128>((int)im));
        im = min(im, (unsigned int)dpp_i<0x142>((int)im));
        im = min(im, (unsigned int)dpp_i<0x143>((int)im));
        int biw = __builtin_amdgcn_readlane((int)im, 63);
        int gi;
        if constexpr (W > 1) {
            unsigned long long key =
                ((unsigned long long)__float_as_uint(bvw) << 32) | (unsigned int)~biw;
            if ((t & 63) == 0) atomicMax(&skey[jm], key);
            __syncthreads();
            unsigned long long gk = skey[jm];
            gi = (int)~(unsigned int)gk;
            // reset the PREVIOUS slot: its readers all passed the barrier we
            // just crossed; its next atomic use is 2 iterations away (after
            // the NEXT barrier), so a plain store here is race-free.
            if (t == 0) skey[jm == 0 ? 2 : jm - 1] = 0;
            jm = (jm == 2) ? 0 : jm + 1;
        } else {
            gi = biw;  // wave-reduced (fixes R9/R10 idx4 bug: was local bi)
        }
        if (t == 0) idx_out[b * M + j] = gi;
        float cx = sx[gi], cy = sy[gi], cz = sz[gi];  // broadcast, conflict-free
#pragma unroll
        for (int i = 0; i < P2; i++)
            dmin[i] = __builtin_elementwise_min(
                dmin[i], sqdist2(px[i], py[i], pz[i], cx, cy, cz));
    }
}

// -------------------------------------------------------------- gather ------
__global__ __launch_bounds__(256) void k_gather(const float* __restrict__ xyz_src,
                                                const int* __restrict__ idx,
                                                float* __restrict__ xyz_dst,
                                                int NS, int M) {
    int i = blockIdx.x * blockDim.x + threadIdx.x;
    if (i >= 2 * M) return;
    int b = i / M;
    int id = idx[i] & (NS - 1);
    xyz_dst[i * 3 + 0] = xyz_src[((size_t)b * NS + id) * 3 + 0];
    xyz_dst[i * 3 + 1] = xyz_src[((size_t)b * NS + id) * 3 + 1];
    xyz_dst[i * 3 + 2] = xyz_src[((size_t)b * NS + id) * 3 + 2];
}

// ------------------------------------------------------------- SetConv ------
template <int NS, int CF, int CMID, int COUT>
__global__ __launch_bounds__(128) void k_setconv(
    const float* __restrict__ X, const unsigned short* __restrict__ F,
    const float* __restrict__ C, const float* __restrict__ w1,
    const float* __restrict__ b1, const float* __restrict__ w2,
    const float* __restrict__ b2, unsigned short* __restrict__ fout,
    float r2, int M) {
    constexpr int CIN = 3 + CF;
    constexpr int K = 16;
    constexpr int M8 = CMID / 8;
    constexpr int O8 = COUT / 8;
    int q = blockIdx.x, b = blockIdx.y;
    int blk = b * M + q;
    const float* Xb = X + (size_t)b * NS * 3;
    const unsigned short* Fb = F + (size_t)b * NS * CF;
    int tid = threadIdx.x;
    __shared__ int s_n[K];
    __shared__ int s_cnt;
    __shared__ float s_h[K][CIN];
    __shared__ float s_mid[K][CMID];
    __shared__ float s_pool[2][COUT];
    float cx = C[(size_t)blk * 3 + 0], cy = C[(size_t)blk * 3 + 1], cz = C[(size_t)blk * 3 + 2];
    if (tid < 64) {
        int lane = tid;
        int cnt = 0;
        for (int base = 0; base < NS; base += 64) {
            int p = base + lane;
            float d2 = sqdist(Xb[p * 3], Xb[p * 3 + 1], Xb[p * 3 + 2], cx, cy, cz);
            bool in = (d2 <= r2);
            unsigned long long msk = __ballot(in);
            if (in) {
                int pos = cnt + __popcll(msk & ((1ull << lane) - 1ull));
                if (pos < K) s_n[pos] = p;
            }
            cnt += __popcll(msk);
            if (cnt >= K) break;
        }
        if (lane == 0) s_cnt = cnt < K ? cnt : K;
    }
    __syncthreads();
    int cnt = s_cnt;
    if (tid >= cnt && tid < K) s_n[tid] = s_n[0];  // pad (center itself always hits)
    __syncthreads();
    for (int tIdx = tid; tIdx < K * CIN; tIdx += 128) {
        int n = tIdx / CIN, c = tIdx % CIN;
        int gi = s_n[n];
        float v;
        if (c < 3) v = __fsub_rn(Xb[gi * 3 + c], (c == 0 ? cx : (c == 1 ? cy : cz)));
        else v = bf2f(Fb[(size_t)gi * CF + (c - 3)]);
        s_h[n][c] = v;
    }
    __syncthreads();
    int n = tid >> 3, sub = tid & 7;
#pragma unroll
    for (int j = 0; j < M8; j++) {
        int m = sub * M8 + j;
        float acc = b1[m];
#pragma unroll 4
        for (int c = 0; c < CIN; c++) acc = fmaf(w1[m * CIN + c], s_h[n][c], acc);
        s_mid[n][m] = fmaxf(acc, 0.f);
    }
    __syncthreads();
    float vals[O8];
#pragma unroll
    for (int j = 0; j < O8; j++) {
        int o = sub * O8 + j;
        float acc = b2[o];
#pragma unroll 4
        for (int c = 0; c < CMID; c++) acc = fmaf(w2[o * CMID + c], s_mid[n][c], acc);
        vals[j] = fmaxf(acc, 0.f);
    }
#pragma unroll
    for (int j = 0; j < O8; j++) {
        vals[j] = fmaxf(vals[j], __shfl_xor(vals[j], 8, 64));
        vals[j] = fmaxf(vals[j], __shfl_xor(vals[j], 16, 64));
        vals[j] = fmaxf(vals[j], __shfl_xor(vals[j], 32, 64));
    }
    int lw = tid & 63, wv = tid >> 6;
    if (lw < 8) {
#pragma unroll
        for (int j = 0; j < O8; j++) s_pool[wv][lw * O8 + j] = vals[j];
    }
    __syncthreads();
    if (tid < 8) {
#pragma unroll
        for (int j = 0; j < O8; j++) {
            int o = tid * O8 + j;
            fout[(size_t)blk * COUT + o] = f2bf(fmaxf(s_pool[0][o], s_pool[1][o]));
        }
    }
}

// ------------------------------------------------------------ SetUpConv -----
template <int S, int CS, int CMID, int CD, int COUT, bool TRANS>
__global__ __launch_bounds__(64) void k_upconv(
    const float* __restrict__ SX, const float* __restrict__ DX,
    const void* __restrict__ SFv, const unsigned short* __restrict__ DF,
    const float* __restrict__ w1, const float* __restrict__ b1,
    const float* __restrict__ w2, const float* __restrict__ b2,
    float* __restrict__ out, int o_off, int ND) {
    constexpr int K = 8;
    constexpr int CIN = 3 + CS;
    constexpr int CIN2 = CMID + CD;
    constexpr int M8 = CMID / 8;
    int q = blockIdx.x, b = blockIdx.y;
    int blk = b * ND + q;
    int lane = threadIdx.x;
    const float* SXb = SX + (size_t)b * S * 3;
    float qx = DX[(size_t)blk * 3], qy = DX[(size_t)blk * 3 + 1], qz = DX[(size_t)blk * 3 + 2];
    __shared__ int s_k[K];
    __shared__ float s_h[K][CIN];
    __shared__ float s_in2[CIN2];
    float bd[K];
    int bi[K];
#pragma unroll
    for (int i = 0; i < K; i++) { bd[i] = 3.0e38f; bi[i] = 0x7fffffff; }
    for (int p = lane; p < S; p += 64) {
        float d2 = sqdist(SXb[p * 3], SXb[p * 3 + 1], SXb[p * 3 + 2], qx, qy, qz);
        if (d2 < bd[K - 1] || (d2 == bd[K - 1] && p < bi[K - 1])) {
            bd[K - 1] = d2; bi[K - 1] = p;
#pragma unroll
            for (int j = K - 1; j > 0; j--) {
                bool sw = (bd[j] < bd[j - 1]) || (bd[j] == bd[j - 1] && bi[j] < bi[j - 1]);
                if (sw) {
                    float tv = bd[j]; bd[j] = bd[j - 1]; bd[j - 1] = tv;
                    int ti = bi[j]; bi[j] = bi[j - 1]; bi[j - 1] = ti;
                }
            }
        }
    }
    for (int r = 0; r < K; r++) {
        float vv = bd[0]; int vi = bi[0];
#pragma unroll
        for (int m = 1; m < 64; m <<= 1) {
            float ov = __shfl_xor(vv, m, 64);
            int oi = __shfl_xor(vi, m, 64);
            if (ov < vv || (ov == vv && oi < vi)) { vv = ov; vi = oi; }
        }
        if (lane == 0) s_k[r] = vi;
        if (vi == bi[0]) {  // unique owner lane pops its head
#pragma unroll
            for (int j = 0; j < K - 1; j++) { bd[j] = bd[j + 1]; bi[j] = bi[j + 1]; }
            bd[K - 1] = 3.0e38f; bi[K - 1] = 0x7fffffff;
        }
    }
    __syncthreads();
    for (int tIdx = lane; tIdx < K * CIN; tIdx += 64) {
        int n = tIdx / CIN, c = tIdx % CIN;
        int gi = s_k[n];
        float v;
        if (c < 3) v = __fsub_rn(SXb[gi * 3 + c], (c == 0 ? qx : (c == 1 ? qy : qz)));
        else if (TRANS) v = ((const float*)SFv)[((size_t)b * CS + (c - 3)) * S + gi];
        else v = bf2f(((const unsigned short*)SFv)[((size_t)b * S + gi) * CS + (c - 3)]);
        s_h[n][c] = v;
    }
    for (int c = lane; c < CD; c += 64) s_in2[CMID + c] = bf2f(DF[(size_t)blk * CD + c]);
    __syncthreads();
    int n = lane >> 3, sub = lane & 7;
    float vals[M8];
#pragma unroll
    for (int j = 0; j < M8; j++) {
        int m = sub * M8 + j;
        float acc = b1[m];
#pragma unroll 4
        for (int c = 0; c < CIN; c++) acc = fmaf(w1[m * CIN + c], s_h[n][c], acc);
        vals[j] = fmaxf(acc, 0.f);
    }
#pragma unroll
    for (int j = 0; j < M8; j++) {
        vals[j] = fmaxf(vals[j], __shfl_xor(vals[j], 8, 64));
        vals[j] = fmaxf(vals[j], __shfl_xor(vals[j], 16, 64));
        vals[j] = fmaxf(vals[j], __shfl_xor(vals[j], 32, 64));
    }
    if (lane < 8) {
#pragma unroll
        for (int j = 0; j < M8; j++) s_in2[lane * M8 + j] = vals[j];
    }
    __syncthreads();
    for (int o = lane; o < COUT; o += 64) {
        float acc = b2[o];
#pragma unroll 4
        for (int c = 0; c < CIN2; c++) acc = fmaf(w2[o * CIN2 + c], s_in2[c], acc);
        out[o_off + ((size_t)b * COUT + o) * ND + q] = fmaxf(acc, 0.f);
    }
}

// ------------------------------------------------------------- finalize -----
__global__ __launch_bounds__(256) void k_finalize(
    const float* __restrict__ xyz1, const float* __restrict__ xyz2,
    const float* __restrict__ xyz3, const int* __restrict__ idx1,
    const int* __restrict__ idx2, const int* __restrict__ idx3,
    float* __restrict__ out) {
    int i = blockIdx.x * blockDim.x + threadIdx.x;
    const float* xs;
    const int* is;
    int M, ox, oi, j;
    if (i < 4096) { xs = xyz1; is = idx1; M = 2048; ox = O_X1; oi = O_I1; j = i; }
    else if (i < 5120) { xs = xyz2; is = idx2; M = 512; ox = O_X2; oi = O_I2; j = i - 4096; }
    else if (i < 5376) { xs = xyz3; is = idx3; M = 128; ox = O_X3; oi = O_I3; j = i - 5120; }
    else return;
    int b = j / M, m = j % M;
    out[ox + (b * 3 + 0) * M + m] = xs[j * 3 + 0];
    out[ox + (b * 3 + 1) * M + m] = xs[j * 3 + 1];
    out[ox + (b * 3 + 2) * M + m] = xs[j * 3 + 2];
    out[oi + j] = (float)is[j];
}

// ---------------------------------------------------------------- launch ----
extern "C" void kernel_launch(void* const* d_in, const int* in_sizes, int n_in,
                              void* d_out, int out_size, void* d_ws, size_t ws_size,
                              hipStream_t stream) {
    const float* pc = (const float*)d_in[0];
    const float* feat = (const float*)d_in[1];
    const float* w0 = (const float*)d_in[2];
    const float* b0v = (const float*)d_in[3];
    const float* sc1w1 = (const float*)d_in[4];  const float* sc1b1 = (const float*)d_in[5];
    const float* sc1w2 = (const float*)d_in[6];  const float* sc1b2 = (const float*)d_in[7];
    const float* sc2w1 = (const float*)d_in[8];  const float* sc2b1 = (const float*)d_in[9];
    const float* sc2w2 = (const float*)d_in[10]; const float* sc2b2 = (const float*)d_in[11];
    const float* sc3w1 = (const float*)d_in[12]; const float* sc3b1 = (const float*)d_in[13];
    const float* sc3w2 = (const float*)d_in[14]; const float* sc3b2 = (const float*)d_in[15];
    const float* sc4w1 = (const float*)d_in[16]; const float* sc4b1 = (const float*)d_in[17];
    const float* sc4w2 = (const float*)d_in[18]; const float* sc4b2 = (const float*)d_in[19];
    const float* up4w1 = (const float*)d_in[20]; const float* up4b1 = (const float*)d_in[21];
    const float* up4w2 = (const float*)d_in[22]; const float* up4b2 = (const float*)d_in[23];
    const float* up3w1 = (const float*)d_in[24]; const float* up3b1 = (const float*)d_in[25];
    const float* up3w2 = (const float*)d_in[26]; const float* up3b2 = (const float*)d_in[27];
    const float* up2w1 = (const float*)d_in[28]; const float* up2b1 = (const float*)d_in[29];
    const float* up2w2 = (const float*)d_in[30]; const float* up2b2 = (const float*)d_in[31];
    const float* up1w1 = (const float*)d_in[32]; const float* up1b1 = (const float*)d_in[33];
    const float* up1w2 = (const float*)d_in[34]; const float* up1b2 = (const float*)d_in[35];
    float* out = (float*)d_out;

    char* ws = (char*)d_ws;
    size_t off = 0;
    auto A = [&](size_t bytes) -> char* {
        char* p = ws + off;
        off += (bytes + 255) & ~(size_t)255;
        return p;
    };
    float* xyz  = (float*)A((size_t)2 * 8192 * 3 * 4);
    int* idx1   = (int*)A((size_t)2 * 2048 * 4);
    int* idx2   = (int*)A((size_t)2 * 512 * 4);
    int* idx3   = (int*)A((size_t)2 * 128 * 4);
    int* idx4   = (int*)A((size_t)2 * 64 * 4);
    float* xyz1 = (float*)A((size_t)2 * 2048 * 3 * 4);
    float* xyz2 = (float*)A((size_t)2 * 512 * 3 * 4);
    float* xyz3 = (float*)A((size_t)2 * 128 * 3 * 4);
    float* xyz4 = (float*)A((size_t)2 * 64 * 3 * 4);
    unsigned short* f0 = (unsigned short*)A((size_t)2 * 8192 * 32 * 2);
    unsigned short* f1 = (unsigned short*)A((size_t)2 * 2048 * 64 * 2);
    unsigned short* f2 = (unsigned short*)A((size_t)2 * 512 * 128 * 2);
    unsigned short* f3 = (unsigned short*)A((size_t)2 * 128 * 192 * 2);
    unsigned short* f4 = (unsigned short*)A((size_t)2 * 64 * 192 * 2);

    k_init<<<(2 * 8192 + 255) / 256, 256, 0, stream>>>(pc, feat, w0, b0v, xyz, f0);

    // ---- down path (ws only)
    k_fps<8192, 2048, 512><<<2, 512, 0, stream>>>(xyz, idx1);
    k_gather<<<16, 256, 0, stream>>>(xyz, idx1, xyz1, 8192, 2048);
    k_setconv<8192, 32, 32, 64><<<dim3(2048, 2), 128, 0, stream>>>(
        xyz, f0, xyz1, sc1w1, sc1b1, sc1w2, sc1b2, f1, 0.25f, 2048);

    k_fps<2048, 512, 512><<<2, 512, 0, stream>>>(xyz1, idx2);
    k_gather<<<4, 256, 0, stream>>>(xyz1, idx2, xyz2, 2048, 512);
    k_setconv<2048, 64, 64, 128><<<dim3(512, 2), 128, 0, stream>>>(
        xyz1, f1, xyz2, sc2w1, sc2b1, sc2w2, sc2b2, f2, 1.0f, 512);

    k_fps<512, 128, 256><<<2, 256, 0, stream>>>(xyz2, idx3);
    k_gather<<<1, 256, 0, stream>>>(xyz2, idx3, xyz3, 512, 128);
    k_setconv<512, 128, 128, 192><<<dim3(128, 2), 128, 0, stream>>>(
        xyz2, f2, xyz3, sc3w1, sc3b1, sc3w2, sc3b2, f3, 4.0f, 128);

    k_fps<128, 64, 64><<<2, 64, 0, stream>>>(xyz3, idx4);
    k_gather<<<1, 128, 0, stream>>>(xyz3, idx4, xyz4, 128, 64);
    k_setconv<128, 192, 192, 192><<<dim3(64, 2), 128, 0, stream>>>(
        xyz3, f3, xyz4, sc4w1, sc4b1, sc4w2, sc4b2, f4, 16.0f, 64);

    // ---- up path: u-features live ONLY in their final out regions (f32)
    k_upconv<64, 192, 192, 192, 192, false><<<dim3(128, 2), 64, 0, stream>>>(
        xyz4, xyz3, f4, f3, up4w1, up4b1, up4w2, up4b2, out, O_U3, 128);
    k_upconv<128, 192, 128, 128, 128, true><<<dim3(512, 2), 64, 0, stream>>>(
        xyz3, xyz2, out + O_U3, f2, up3w1, up3b1, up3w2, up3b2, out, O_U2, 512);
    k_upconv<512, 128, 64, 64, 64, true><<<dim3(2048, 2), 64, 0, stream>>>(
        xyz2, xyz1, out + O_U2, f1, up2w1, up2b1, up2w2, up2b2, out, O_U1, 2048);
    k_upconv<2048, 64, 32, 32, 32, true><<<dim3(8192, 2), 64, 0, stream>>>(
        xyz1, xyz, out + O_U1, f0, up1w1, up1b1, up1w2, up1b2, out, O_U0, 8192);

    // ---- x/i outputs written last
    k_finalize<<<(5376 + 255) / 256, 256, 0, stream>>>(
        xyz1, xyz2, xyz3, idx1, idx2, idx3, out);
}

// Round 12
// 3846.170 us; speedup vs baseline: 1.2861x; 1.0521x over previous
//
#include <hip/hip_runtime.h>
#include <hip/hip_bf16.h>
#include <cstdint>

#define DEV __device__ __forceinline__

typedef float f32x2 __attribute__((ext_vector_type(2)));

DEV float sqdist(float ax, float ay, float az, float bx, float by, float bz) {
    float dx = __fsub_rn(ax, bx), dy = __fsub_rn(ay, by), dz = __fsub_rn(az, bz);
    return __fadd_rn(__fadd_rn(__fmul_rn(dx, dx), __fmul_rn(dy, dy)), __fmul_rn(dz, dz));
}

// Element-wise IEEE rn sub/mul/add with contraction OFF == bit-identical to
// the scalar chain, but packs into v_pk_* ops.
DEV f32x2 sqdist2(f32x2 ax, f32x2 ay, f32x2 az, float bx, float by, float bz) {
#pragma clang fp contract(off)
    f32x2 dx = ax - bx, dy = ay - by, dz = az - bz;
    return (dx * dx + dy * dy) + dz * dz;
}

DEV unsigned short f2bf(float f) {
    unsigned int u = __float_as_uint(f);
    u += 0x7fffu + ((u >> 16) & 1u);
    return (unsigned short)(u >> 16);
}

DEV float bf2f(unsigned short u) { return __uint_as_float(((unsigned int)u) << 16); }

template <int CTRL>
DEV int dpp_i(int v) { return __builtin_amdgcn_update_dpp(v, v, CTRL, 0xf, 0xf, false); }
template <int CTRL>
DEV float dpp_f(float v) { return __int_as_float(dpp_i<CTRL>(__float_as_int(v))); }

// Output offsets (f32 elements) in return order.
enum : int {
    O_X1 = 0, O_X2 = 12288, O_X3 = 15360,
    O_I1 = 16128, O_I2 = 20224, O_I3 = 21248,
    O_U0 = 21504, O_U1 = 545792, O_U2 = 807936, O_U3 = 939008
};

// ---------------------------------------------------------------- init ------
__global__ __launch_bounds__(256) void k_init(const float* __restrict__ pc,
                                              const float* __restrict__ feat,
                                              const float* __restrict__ w0,
                                              const float* __restrict__ b0,
                                              float* __restrict__ xyz,
                                              unsigned short* __restrict__ f0) {
    const int N = 8192;
    int i = blockIdx.x * blockDim.x + threadIdx.x;
    if (i >= 2 * N) return;
    int b = i / N, n = i % N;
    float fx0 = feat[(b * 3 + 0) * N + n];
    float fx1 = feat[(b * 3 + 1) * N + n];
    float fx2 = feat[(b * 3 + 2) * N + n];
    xyz[i * 3 + 0] = pc[(b * 3 + 0) * N + n];
    xyz[i * 3 + 1] = pc[(b * 3 + 1) * N + n];
    xyz[i * 3 + 2] = pc[(b * 3 + 2) * N + n];
#pragma unroll
    for (int o = 0; o < 32; o++) {
        float acc = b0[o];
        acc = fmaf(w0[o * 3 + 0], fx0, acc);
        acc = fmaf(w0[o * 3 + 1], fx1, acc);
        acc = fmaf(w0[o * 3 + 2], fx2, acc);
        f0[(size_t)i * 32 + o] = f2bf(fmaxf(acc, 0.f));
    }
}

// ------------------------------------------------------------ FPS body ------
// Identical logic to the R11-proven kernel; smem carved from a char blob so
// the body can be embedded in fused kernels. bytes = 12*N + 24.
template <int N, int M, int T>
DEV void fps_body(int b, int t, const float* __restrict__ xyz,
                  int* __restrict__ idx_out, char* smem) {
    constexpr int P = N / T;
    constexpr int P2 = P / 2;
    constexpr int W = T / 64;
    const float* X = xyz + (size_t)b * N * 3;
    float* sx = (float*)smem;
    float* sy = sx + N;
    float* sz = sy + N;
    unsigned long long* skey = (unsigned long long*)(smem + 12 * N);
    f32x2 px[P2], py[P2], pz[P2], dmin[P2];
    float c0x = X[0], c0y = X[1], c0z = X[2];
#pragma unroll
    for (int i = 0; i < P2; i++) {
        int p0 = (2 * i) * T + t, p1 = (2 * i + 1) * T + t;
        px[i] = f32x2{X[p0 * 3 + 0], X[p1 * 3 + 0]};
        py[i] = f32x2{X[p0 * 3 + 1], X[p1 * 3 + 1]};
        pz[i] = f32x2{X[p0 * 3 + 2], X[p1 * 3 + 2]};
        sx[p0] = px[i].x; sy[p0] = py[i].x; sz[p0] = pz[i].x;
        sx[p1] = px[i].y; sy[p1] = py[i].y; sz[p1] = pz[i].y;
        dmin[i] = sqdist2(px[i], py[i], pz[i], c0x, c0y, c0z);
    }
    if (t == 0) {
        idx_out[b * M] = 0;
        skey[0] = 0; skey[1] = 0; skey[2] = 0;
    }
    __syncthreads();
    int jm = 1;
    for (int j = 1; j < M; j++) {
        f32x2 m2[P2];
#pragma unroll
        for (int i = 0; i < P2; i++) m2[i] = dmin[i];
#pragma unroll
        for (int s = P2 / 2; s >= 1; s >>= 1)
#pragma unroll
            for (int i = 0; i < s; i++) m2[i] = __builtin_elementwise_max(m2[i], m2[i + s]);
        float bv = fmaxf(m2[0].x, m2[0].y);
        int ii[P];
#pragma unroll
        for (int i = 0; i < P; i++)
            ii[i] = (dmin[i >> 1][i & 1] == bv) ? (i * T + t) : 0x7fffffff;
#pragma unroll
        for (int s = P / 2; s >= 1; s >>= 1)
#pragma unroll
            for (int i = 0; i < s; i++) ii[i] = min(ii[i], ii[i + s]);
        int bi = ii[0];
        // wave reduce: fmax DPP chain -> lane 63; masked u32-min chain
        float bw = bv;
        bw = fmaxf(bw, dpp_f<0x121>(bw));
        bw = fmaxf(bw, dpp_f<0x122>(bw));
        bw = fmaxf(bw, dpp_f<0x124>(bw));
        bw = fmaxf(bw, dpp_f<0x128>(bw));
        bw = fmaxf(bw, dpp_f<0x142>(bw));
        bw = fmaxf(bw, dpp_f<0x143>(bw));
        float bvw = __int_as_float(__builtin_amdgcn_readlane(__float_as_int(bw), 63));
        unsigned int im = (bv == bvw) ? (unsigned int)bi : 0xffffffffu;
        im = min(im, (unsigned int)dpp_i<0x121>((int)im));
        im = min(im, (unsigned int)dpp_i<0x122>((int)im));
        im = min(im, (unsigned int)dpp_i<0x124>((int)im));
        im = min(im, (unsigned int)dpp_i<0x128>((int)im));
        im = min(im, (unsigned int)dpp_i<0x142>((int)im));
        im = min(im, (unsigned int)dpp_i<0x143>((int)im));
        int biw = __builtin_amdgcn_readlane((int)im, 63);
        int gi;
        if constexpr (W > 1) {
            unsigned long long key =
                ((unsigned long long)__float_as_uint(bvw) << 32) | (unsigned int)~biw;
            if ((t & 63) == 0) atomicMax(&skey[jm], key);
            __syncthreads();
            unsigned long long gk = skey[jm];
            gi = (int)~(unsigned int)gk;
            if (t == 0) skey[jm == 0 ? 2 : jm - 1] = 0;
            jm = (jm == 2) ? 0 : jm + 1;
        } else {
            gi = biw;
        }
        if (t == 0) idx_out[b * M + j] = gi;
        float cx = sx[gi], cy = sy[gi], cz = sz[gi];
#pragma unroll
        for (int i = 0; i < P2; i++)
            dmin[i] = __builtin_elementwise_min(
                dmin[i], sqdist2(px[i], py[i], pz[i], cx, cy, cz));
    }
}

template <int N, int M, int T>
__global__ __launch_bounds__(T, 1) void k_fps(const float* __restrict__ xyz,
                                              int* __restrict__ idx_out) {
    __shared__ __align__(16) char smem[12 * N + 24];
    fps_body<N, M, T>(blockIdx.x, threadIdx.x, xyz, idx_out, smem);
}

// -------------------------------------------------------------- gather ------
__global__ __launch_bounds__(256) void k_gather(const float* __restrict__ xyz_src,
                                                const int* __restrict__ idx,
                                                float* __restrict__ xyz_dst,
                                                int NS, int M) {
    int i = blockIdx.x * blockDim.x + threadIdx.x;
    if (i >= 2 * M) return;
    int b = i / M;
    int id = idx[i] & (NS - 1);
    xyz_dst[i * 3 + 0] = xyz_src[((size_t)b * NS + id) * 3 + 0];
    xyz_dst[i * 3 + 1] = xyz_src[((size_t)b * NS + id) * 3 + 1];
    xyz_dst[i * 3 + 2] = xyz_src[((size_t)b * NS + id) * 3 + 2];
}

// --------------------------------------------------------- SetConv body -----
// Flexible blockDim (>=128, multiple of 64): ballot phase on wave 0, staging
// striped across all threads, MLP phases guarded to tid<128, barriers at top
// level. smem bytes = 80 + 4*(K*CIN + K*CMID + 2*COUT).
template <int NS, int CF, int CMID, int COUT>
DEV void setconv_body(int q, int bb, int tid, int bdim,
                      const float* __restrict__ X, const unsigned short* __restrict__ F,
                      const float* __restrict__ C, const float* __restrict__ w1,
                      const float* __restrict__ b1, const float* __restrict__ w2,
                      const float* __restrict__ b2, unsigned short* __restrict__ fout,
                      float r2, int M, char* smem) {
    constexpr int CIN = 3 + CF;
    constexpr int K = 16;
    constexpr int M8 = CMID / 8;
    constexpr int O8 = COUT / 8;
    int blk = bb * M + q;
    const float* Xb = X + (size_t)bb * NS * 3;
    const unsigned short* Fb = F + (size_t)bb * NS * CF;
    int* s_n = (int*)smem;
    int* s_cntp = (int*)(smem + 64);
    float* s_h = (float*)(smem + 80);            // [K][CIN]
    float* s_mid = s_h + K * CIN;                // [K][CMID]
    float* s_pool = s_mid + K * CMID;            // [2][COUT]
    float cx = C[(size_t)blk * 3 + 0], cy = C[(size_t)blk * 3 + 1], cz = C[(size_t)blk * 3 + 2];
    if (tid < 64) {
        int lane = tid;
        int cnt = 0;
        for (int base = 0; base < NS; base += 64) {
            int p = base + lane;
            float d2 = sqdist(Xb[p * 3], Xb[p * 3 + 1], Xb[p * 3 + 2], cx, cy, cz);
            bool in = (d2 <= r2);
            unsigned long long msk = __ballot(in);
            if (in) {
                int pos = cnt + __popcll(msk & ((1ull << lane) - 1ull));
                if (pos < K) s_n[pos] = p;
            }
            cnt += __popcll(msk);
            if (cnt >= K) break;
        }
        if (lane == 0) *s_cntp = cnt < K ? cnt : K;
    }
    __syncthreads();
    int cnt = *s_cntp;
    if (tid >= cnt && tid < K) s_n[tid] = s_n[0];  // pad (center itself always hits)
    __syncthreads();
    for (int tIdx = tid; tIdx < K * CIN; tIdx += bdim) {
        int n = tIdx / CIN, c = tIdx % CIN;
        int gi = s_n[n];
        float v;
        if (c < 3) v = __fsub_rn(Xb[gi * 3 + c], (c == 0 ? cx : (c == 1 ? cy : cz)));
        else v = bf2f(Fb[(size_t)gi * CF + (c - 3)]);
        s_h[n * CIN + c] = v;
    }
    __syncthreads();
    if (tid < 128) {
        int n = tid >> 3, sub = tid & 7;
#pragma unroll
        for (int j = 0; j < M8; j++) {
            int m = sub * M8 + j;
            float acc = b1[m];
#pragma unroll 4
            for (int c = 0; c < CIN; c++) acc = fmaf(w1[m * CIN + c], s_h[n * CIN + c], acc);
            s_mid[n * CMID + m] = fmaxf(acc, 0.f);
        }
    }
    __syncthreads();
    if (tid < 128) {
        int n = tid >> 3, sub = tid & 7;
        float vals[O8];
#pragma unroll
        for (int j = 0; j < O8; j++) {
            int o = sub * O8 + j;
            float acc = b2[o];
#pragma unroll 4
            for (int c = 0; c < CMID; c++) acc = fmaf(w2[o * CMID + c], s_mid[n * CMID + c], acc);
            vals[j] = fmaxf(acc, 0.f);
        }
#pragma unroll
        for (int j = 0; j < O8; j++) {
            vals[j] = fmaxf(vals[j], __shfl_xor(vals[j], 8, 64));
            vals[j] = fmaxf(vals[j], __shfl_xor(vals[j], 16, 64));
            vals[j] = fmaxf(vals[j], __shfl_xor(vals[j], 32, 64));
        }
        int lw = tid & 63, wv = tid >> 6;
        if (lw < 8) {
#pragma unroll
            for (int j = 0; j < O8; j++) s_pool[wv * COUT + lw * O8 + j] = vals[j];
        }
    }
    __syncthreads();
    if (tid < 8) {
#pragma unroll
        for (int j = 0; j < O8; j++) {
            int o = tid * O8 + j;
            fout[(size_t)blk * COUT + o] = f2bf(fmaxf(s_pool[o], s_pool[COUT + o]));
        }
    }
}

template <int NS, int CF, int CMID, int COUT>
__global__ __launch_bounds__(128) void k_setconv(
    const float* __restrict__ X, const unsigned short* __restrict__ F,
    const float* __restrict__ C, const float* __restrict__ w1,
    const float* __restrict__ b1, const float* __restrict__ w2,
    const float* __restrict__ b2, unsigned short* __restrict__ fout,
    float r2, int M) {
    constexpr int K = 16;
    constexpr int CIN = 3 + CF;
    __shared__ __align__(16) char smem[80 + 4 * (K * CIN + K * CMID + 2 * COUT)];
    setconv_body<NS, CF, CMID, COUT>(blockIdx.x, blockIdx.y, threadIdx.x, blockDim.x,
                                     X, F, C, w1, b1, w2, b2, fout, r2, M, smem);
}

// --------------------------------------------- fused FPS + SetConv ----------
// blocks 0..1: FPS of the NEXT level; blocks 2..2+2*Msc: setconv of the
// CURRENT level (independent work; both depend only on the preceding gather).
template <int N, int M, int T, int NS, int CF, int CMID, int COUT>
__global__ __launch_bounds__(T, 1) void k_fps_sc(
    const float* __restrict__ fxyz, int* __restrict__ idx_out,
    const float* __restrict__ X, const unsigned short* __restrict__ F,
    const float* __restrict__ C, const float* __restrict__ w1,
    const float* __restrict__ b1, const float* __restrict__ w2,
    const float* __restrict__ b2, unsigned short* __restrict__ fout,
    float r2, int Msc) {
    constexpr int K = 16;
    constexpr int CIN = 3 + CF;
    constexpr int FPS_B = 12 * N + 24;
    constexpr int SC_B = 80 + 4 * (K * CIN + K * CMID + 2 * COUT);
    constexpr int SB = FPS_B > SC_B ? FPS_B : SC_B;
    __shared__ __align__(16) char smem[SB];
    if (blockIdx.x < 2) {
        fps_body<N, M, T>(blockIdx.x, threadIdx.x, fxyz, idx_out, smem);
    } else {
        int lin = blockIdx.x - 2;
        int q = lin % Msc, bb = lin / Msc;
        setconv_body<NS, CF, CMID, COUT>(q, bb, threadIdx.x, blockDim.x,
                                         X, F, C, w1, b1, w2, b2, fout, r2, Msc, smem);
    }
}

// ------------------------------------------------------------ SetUpConv -----
template <int S, int CS, int CMID, int CD, int COUT, bool TRANS>
__global__ __launch_bounds__(64) void k_upconv(
    const float* __restrict__ SX, const float* __restrict__ DX,
    const void* __restrict__ SFv, const unsigned short* __restrict__ DF,
    const float* __restrict__ w1, const float* __restrict__ b1,
    const float* __restrict__ w2, const float* __restrict__ b2,
    float* __restrict__ out, int o_off, int ND) {
    constexpr int K = 8;
    constexpr int CIN = 3 + CS;
    constexpr int CIN2 = CMID + CD;
    constexpr int M8 = CMID / 8;
    int q = blockIdx.x, b = blockIdx.y;
    int blk = b * ND + q;
    int lane = threadIdx.x;
    const float* SXb = SX + (size_t)b * S * 3;
    float qx = DX[(size_t)blk * 3], qy = DX[(size_t)blk * 3 + 1], qz = DX[(size_t)blk * 3 + 2];
    __shared__ int s_k[K];
    __shared__ float s_h[K][CIN];
    __shared__ float s_in2[CIN2];
    float bd[K];
    int bi[K];
#pragma unroll
    for (int i = 0; i < K; i++) { bd[i] = 3.0e38f; bi[i] = 0x7fffffff; }
    for (int p = lane; p < S; p += 64) {
        float d2 = sqdist(SXb[p * 3], SXb[p * 3 + 1], SXb[p * 3 + 2], qx, qy, qz);
        if (d2 < bd[K - 1] || (d2 == bd[K - 1] && p < bi[K - 1])) {
            bd[K - 1] = d2; bi[K - 1] = p;
#pragma unroll
            for (int j = K - 1; j > 0; j--) {
                bool sw = (bd[j] < bd[j - 1]) || (bd[j] == bd[j - 1] && bi[j] < bi[j - 1]);
                if (sw) {
                    float tv = bd[j]; bd[j] = bd[j - 1]; bd[j - 1] = tv;
                    int ti = bi[j]; bi[j] = bi[j - 1]; bi[j - 1] = ti;
                }
            }
        }
    }
    // 8 rounds of wave argmin via two single-op DPP chains + readlane
    for (int r = 0; r < K; r++) {
        float vv = bd[0];
        float bw = vv;
        bw = fminf(bw, dpp_f<0x121>(bw));
        bw = fminf(bw, dpp_f<0x122>(bw));
        bw = fminf(bw, dpp_f<0x124>(bw));
        bw = fminf(bw, dpp_f<0x128>(bw));
        bw = fminf(bw, dpp_f<0x142>(bw));
        bw = fminf(bw, dpp_f<0x143>(bw));
        float vw = __int_as_float(__builtin_amdgcn_readlane(__float_as_int(bw), 63));
        unsigned int im = (vv == vw) ? (unsigned int)bi[0] : 0xffffffffu;
        im = min(im, (unsigned int)dpp_i<0x121>((int)im));
        im = min(im, (unsigned int)dpp_i<0x122>((int)im));
        im = min(im, (unsigned int)dpp_i<0x124>((int)im));
        im = min(im, (unsigned int)dpp_i<0x128>((int)im));
        im = min(im, (unsigned int)dpp_i<0x142>((int)im));
        im = min(im, (unsigned int)dpp_i<0x143>((int)im));
        int iw = __builtin_amdgcn_readlane((int)im, 63);
        if (lane == 0) s_k[r] = iw;
        if (iw == bi[0]) {  // unique owner lane pops its head
#pragma unroll
            for (int j = 0; j < K - 1; j++) { bd[j] = bd[j + 1]; bi[j] = bi[j + 1]; }
            bd[K - 1] = 3.0e38f; bi[K - 1] = 0x7fffffff;
        }
    }
    __syncthreads();
    for (int tIdx = lane; tIdx < K * CIN; tIdx += 64) {
        int n = tIdx / CIN, c = tIdx % CIN;
        int gi = s_k[n];
        float v;
        if (c < 3) v = __fsub_rn(SXb[gi * 3 + c], (c == 0 ? qx : (c == 1 ? qy : qz)));
        else if (TRANS) v = ((const float*)SFv)[((size_t)b * CS + (c - 3)) * S + gi];
        else v = bf2f(((const unsigned short*)SFv)[((size_t)b * S + gi) * CS + (c - 3)]);
        s_h[n][c] = v;
    }
    for (int c = lane; c < CD; c += 64) s_in2[CMID + c] = bf2f(DF[(size_t)blk * CD + c]);
    __syncthreads();
    int n = lane >> 3, sub = lane & 7;
    float vals[M8];
#pragma unroll
    for (int j = 0; j < M8; j++) {
        int m = sub * M8 + j;
        float acc = b1[m];
#pragma unroll 4
        for (int c = 0; c < CIN; c++) acc = fmaf(w1[m * CIN + c], s_h[n][c], acc);
        vals[j] = fmaxf(acc, 0.f);
    }
#pragma unroll
    for (int j = 0; j < M8; j++) {
        vals[j] = fmaxf(vals[j], __shfl_xor(vals[j], 8, 64));
        vals[j] = fmaxf(vals[j], __shfl_xor(vals[j], 16, 64));
        vals[j] = fmaxf(vals[j], __shfl_xor(vals[j], 32, 64));
    }
    if (lane < 8) {
#pragma unroll
        for (int j = 0; j < M8; j++) s_in2[lane * M8 + j] = vals[j];
    }
    __syncthreads();
    for (int o = lane; o < COUT; o += 64) {
        float acc = b2[o];
#pragma unroll 4
        for (int c = 0; c < CIN2; c++) acc = fmaf(w2[o * CIN2 + c], s_in2[c], acc);
        out[o_off + ((size_t)b * COUT + o) * ND + q] = fmaxf(acc, 0.f);
    }
}

// ------------------------------------------------------------- finalize -----
__global__ __launch_bounds__(256) void k_finalize(
    const float* __restrict__ xyz1, const float* __restrict__ xyz2,
    const float* __restrict__ xyz3, const int* __restrict__ idx1,
    const int* __restrict__ idx2, const int* __restrict__ idx3,
    float* __restrict__ out) {
    int i = blockIdx.x * blockDim.x + threadIdx.x;
    const float* xs;
    const int* is;
    int M, ox, oi, j;
    if (i < 4096) { xs = xyz1; is = idx1; M = 2048; ox = O_X1; oi = O_I1; j = i; }
    else if (i < 5120) { xs = xyz2; is = idx2; M = 512; ox = O_X2; oi = O_I2; j = i - 4096; }
    else if (i < 5376) { xs = xyz3; is = idx3; M = 128; ox = O_X3; oi = O_I3; j = i - 5120; }
    else return;
    int b = j / M, m = j % M;
    out[ox + (b * 3 + 0) * M + m] = xs[j * 3 + 0];
    out[ox + (b * 3 + 1) * M + m] = xs[j * 3 + 1];
    out[ox + (b * 3 + 2) * M + m] = xs[j * 3 + 2];
    out[oi + j] = (float)is[j];
}

// ---------------------------------------------------------------- launch ----
extern "C" void kernel_launch(void* const* d_in, const int* in_sizes, int n_in,
                              void* d_out, int out_size, void* d_ws, size_t ws_size,
                              hipStream_t stream) {
    const float* pc = (const float*)d_in[0];
    const float* feat = (const float*)d_in[1];
    const float* w0 = (const float*)d_in[2];
    const float* b0v = (const float*)d_in[3];
    const float* sc1w1 = (const float*)d_in[4];  const float* sc1b1 = (const float*)d_in[5];
    const float* sc1w2 = (const float*)d_in[6];  const float* sc1b2 = (const float*)d_in[7];
    const float* sc2w1 = (const float*)d_in[8];  const float* sc2b1 = (const float*)d_in[9];
    const float* sc2w2 = (const float*)d_in[10]; const float* sc2b2 = (const float*)d_in[11];
    const float* sc3w1 = (const float*)d_in[12]; const float* sc3b1 = (const float*)d_in[13];
    const float* sc3w2 = (const float*)d_in[14]; const float* sc3b2 = (const float*)d_in[15];
    const float* sc4w1 = (const float*)d_in[16]; const float* sc4b1 = (const float*)d_in[17];
    const float* sc4w2 = (const float*)d_in[18]; const float* sc4b2 = (const float*)d_in[19];
    const float* up4w1 = (const float*)d_in[20]; const float* up4b1 = (const float*)d_in[21];
    const float* up4w2 = (const float*)d_in[22]; const float* up4b2 = (const float*)d_in[23];
    const float* up3w1 = (const float*)d_in[24]; const float* up3b1 = (const float*)d_in[25];
    const float* up3w2 = (const float*)d_in[26]; const float* up3b2 = (const float*)d_in[27];
    const float* up2w1 = (const float*)d_in[28]; const float* up2b1 = (const float*)d_in[29];
    const float* up2w2 = (const float*)d_in[30]; const float* up2b2 = (const float*)d_in[31];
    const float* up1w1 = (const float*)d_in[32]; const float* up1b1 = (const float*)d_in[33];
    const float* up1w2 = (const float*)d_in[34]; const float* up1b2 = (const float*)d_in[35];
    float* out = (float*)d_out;

    char* ws = (char*)d_ws;
    size_t off = 0;
    auto A = [&](size_t bytes) -> char* {
        char* p = ws + off;
        off += (bytes + 255) & ~(size_t)255;
        return p;
    };
    float* xyz  = (float*)A((size_t)2 * 8192 * 3 * 4);
    int* idx1   = (int*)A((size_t)2 * 2048 * 4);
    int* idx2   = (int*)A((size_t)2 * 512 * 4);
    int* idx3   = (int*)A((size_t)2 * 128 * 4);
    int* idx4   = (int*)A((size_t)2 * 64 * 4);
    float* xyz1 = (float*)A((size_t)2 * 2048 * 3 * 4);
    float* xyz2 = (float*)A((size_t)2 * 512 * 3 * 4);
    float* xyz3 = (float*)A((size_t)2 * 128 * 3 * 4);
    float* xyz4 = (float*)A((size_t)2 * 64 * 3 * 4);
    unsigned short* f0 = (unsigned short*)A((size_t)2 * 8192 * 32 * 2);
    unsigned short* f1 = (unsigned short*)A((size_t)2 * 2048 * 64 * 2);
    unsigned short* f2 = (unsigned short*)A((size_t)2 * 512 * 128 * 2);
    unsigned short* f3 = (unsigned short*)A((size_t)2 * 128 * 192 * 2);
    unsigned short* f4 = (unsigned short*)A((size_t)2 * 64 * 192 * 2);

    k_init<<<(2 * 8192 + 255) / 256, 256, 0, stream>>>(pc, feat, w0, b0v, xyz, f0);

    // ---- down path
    k_fps<8192, 2048, 512><<<2, 512, 0, stream>>>(xyz, idx1);
    k_gather<<<16, 256, 0, stream>>>(xyz, idx1, xyz1, 8192, 2048);
    // fps level-2 (blocks 0-1) runs concurrently with setconv level-1
    k_fps_sc<2048, 512, 512, 8192, 32, 32, 64><<<2 + 2 * 2048, 512, 0, stream>>>(
        xyz1, idx2, xyz, f0, xyz1, sc1w1, sc1b1, sc1w2, sc1b2, f1, 0.25f, 2048);
    k_gather<<<4, 256, 0, stream>>>(xyz1, idx2, xyz2, 2048, 512);
    // fps level-3 + setconv level-2
    k_fps_sc<512, 128, 256, 2048, 64, 64, 128><<<2 + 2 * 512, 256, 0, stream>>>(
        xyz2, idx3, xyz1, f1, xyz2, sc2w1, sc2b1, sc2w2, sc2b2, f2, 1.0f, 512);
    k_gather<<<1, 256, 0, stream>>>(xyz2, idx3, xyz3, 512, 128);
    k_fps<128, 64, 64><<<2, 64, 0, stream>>>(xyz3, idx4);
    k_gather<<<1, 128, 0, stream>>>(xyz3, idx4, xyz4, 128, 64);
    k_setconv<512, 128, 128, 192><<<dim3(128, 2), 128, 0, stream>>>(
        xyz2, f2, xyz3, sc3w1, sc3b1, sc3w2, sc3b2, f3, 4.0f, 128);
    k_setconv<128, 192, 192, 192><<<dim3(64, 2), 128, 0, stream>>>(
        xyz3, f3, xyz4, sc4w1, sc4b1, sc4w2, sc4b2, f4, 16.0f, 64);

    // ---- up path (sequential deps; u-features live in final out regions)
    k_upconv<64, 192, 192, 192, 192, false><<<dim3(128, 2), 64, 0, stream>>>(
        xyz4, xyz3, f4, f3, up4w1, up4b1, up4w2, up4b2, out, O_U3, 128);
    k_upconv<128, 192, 128, 128, 128, true><<<dim3(512, 2), 64, 0, stream>>>(
        xyz3, xyz2, out + O_U3, f2, up3w1, up3b1, up3w2, up3b2, out, O_U2, 512);
    k_upconv<512, 128, 64, 64, 64, true><<<dim3(2048, 2), 64, 0, stream>>>(
        xyz2, xyz1, out + O_U2, f1, up2w1, up2b1, up2w2, up2b2, out, O_U1, 2048);
    k_upconv<2048, 64, 32, 32, 32, true><<<dim3(8192, 2), 64, 0, stream>>>(
        xyz1, xyz, out + O_U1, f0, up1w1, up1b1, up1w2, up1b2, out, O_U0, 8192);

    // ---- x/i outputs written last
    k_finalize<<<(5376 + 255) / 256, 256, 0, stream>>>(
        xyz1, xyz2, xyz3, idx1, idx2, idx3, out);
}

// Round 13
// 3659.542 us; speedup vs baseline: 1.3517x; 1.0510x over previous
//
#include <hip/hip_runtime.h>
#include <hip/hip_bf16.h>
#include <cstdint>

#define DEV __device__ __forceinline__

typedef float f32x2 __attribute__((ext_vector_type(2)));

DEV float sqdist(float ax, float ay, float az, float bx, float by, float bz) {
    float dx = __fsub_rn(ax, bx), dy = __fsub_rn(ay, by), dz = __fsub_rn(az, bz);
    return __fadd_rn(__fadd_rn(__fmul_rn(dx, dx), __fmul_rn(dy, dy)), __fmul_rn(dz, dz));
}

// Element-wise IEEE rn sub/mul/add with contraction OFF == bit-identical to
// the scalar chain, but packs into v_pk_* ops.
DEV f32x2 sqdist2(f32x2 ax, f32x2 ay, f32x2 az, float bx, float by, float bz) {
#pragma clang fp contract(off)
    f32x2 dx = ax - bx, dy = ay - by, dz = az - bz;
    return (dx * dx + dy * dy) + dz * dz;
}

DEV unsigned short f2bf(float f) {
    unsigned int u = __float_as_uint(f);
    u += 0x7fffu + ((u >> 16) & 1u);
    return (unsigned short)(u >> 16);
}

DEV float bf2f(unsigned short u) { return __uint_as_float(((unsigned int)u) << 16); }

template <int CTRL>
DEV int dpp_i(int v) { return __builtin_amdgcn_update_dpp(v, v, CTRL, 0xf, 0xf, false); }
template <int CTRL>
DEV float dpp_f(float v) { return __int_as_float(dpp_i<CTRL>(__float_as_int(v))); }

// Output offsets (f32 elements) in return order.
enum : int {
    O_X1 = 0, O_X2 = 12288, O_X3 = 15360,
    O_I1 = 16128, O_I2 = 20224, O_I3 = 21248,
    O_U0 = 21504, O_U1 = 545792, O_U2 = 807936, O_U3 = 939008
};

// ---------------------------------------------------------------- init ------
__global__ __launch_bounds__(256) void k_init(const float* __restrict__ pc,
                                              const float* __restrict__ feat,
                                              const float* __restrict__ w0,
                                              const float* __restrict__ b0,
                                              float* __restrict__ xyz,
                                              unsigned short* __restrict__ f0) {
    const int N = 8192;
    int i = blockIdx.x * blockDim.x + threadIdx.x;
    if (i >= 2 * N) return;
    int b = i / N, n = i % N;
    float fx0 = feat[(b * 3 + 0) * N + n];
    float fx1 = feat[(b * 3 + 1) * N + n];
    float fx2 = feat[(b * 3 + 2) * N + n];
    xyz[i * 3 + 0] = pc[(b * 3 + 0) * N + n];
    xyz[i * 3 + 1] = pc[(b * 3 + 1) * N + n];
    xyz[i * 3 + 2] = pc[(b * 3 + 2) * N + n];
#pragma unroll
    for (int o = 0; o < 32; o++) {
        float acc = b0[o];
        acc = fmaf(w0[o * 3 + 0], fx0, acc);
        acc = fmaf(w0[o * 3 + 1], fx1, acc);
        acc = fmaf(w0[o * 3 + 2], fx2, acc);
        f0[(size_t)i * 32 + o] = f2bf(fmaxf(acc, 0.f));
    }
}

// -------------------------------------------------- spatial binning ---------
// Per batch (one block, T threads): 8x8x8 counting sort of the N points into
// SoA permuted arrays xp/yp/zp + original-id map pid. Values are COPIED
// exactly; only the order changes, so all downstream distances are exact.
template <int N, int T>
__global__ __launch_bounds__(T) void k_bin(const float* __restrict__ xyz,
                                           float* __restrict__ xp, float* __restrict__ yp,
                                           float* __restrict__ zp, int* __restrict__ pid) {
    constexpr int W = T / 64;
    int b = blockIdx.x, t = threadIdx.x;
    const float* X = xyz + (size_t)b * N * 3;
    __shared__ float smn[3][W], smx[3][W];
    __shared__ int hist[512], scan[512], cnt[512];
    float mn[3] = {3e38f, 3e38f, 3e38f}, mx[3] = {-3e38f, -3e38f, -3e38f};
    for (int p = t; p < N; p += T) {
        float v[3] = {X[p * 3], X[p * 3 + 1], X[p * 3 + 2]};
#pragma unroll
        for (int a = 0; a < 3; a++) { mn[a] = fminf(mn[a], v[a]); mx[a] = fmaxf(mx[a], v[a]); }
    }
#pragma unroll
    for (int a = 0; a < 3; a++) {
#pragma unroll
        for (int m = 1; m < 64; m <<= 1) {
            mn[a] = fminf(mn[a], __shfl_xor(mn[a], m, 64));
            mx[a] = fmaxf(mx[a], __shfl_xor(mx[a], m, 64));
        }
    }
    if ((t & 63) == 0) {
#pragma unroll
        for (int a = 0; a < 3; a++) { smn[a][t >> 6] = mn[a]; smx[a][t >> 6] = mx[a]; }
    }
    for (int i = t; i < 512; i += T) { hist[i] = 0; cnt[i] = 0; }
    __syncthreads();
#pragma unroll
    for (int a = 0; a < 3; a++) {
        mn[a] = smn[a][0]; mx[a] = smx[a][0];
#pragma unroll
        for (int w = 1; w < W; w++) { mn[a] = fminf(mn[a], smn[a][w]); mx[a] = fmaxf(mx[a], smx[a][w]); }
    }
    float inv[3];
#pragma unroll
    for (int a = 0; a < 3; a++) inv[a] = 8.0f / fmaxf(mx[a] - mn[a], 1e-9f);
    auto bin_of = [&](float x, float y, float z) {
        int ix = min(7, max(0, (int)((x - mn[0]) * inv[0])));
        int iy = min(7, max(0, (int)((y - mn[1]) * inv[1])));
        int iz = min(7, max(0, (int)((z - mn[2]) * inv[2])));
        return (ix << 6) | (iy << 3) | iz;
    };
    for (int p = t; p < N; p += T) {
        atomicAdd(&hist[bin_of(X[p * 3], X[p * 3 + 1], X[p * 3 + 2])], 1);
    }
    __syncthreads();
    if (t < 512) scan[t] = hist[t];
    __syncthreads();
    for (int s = 1; s < 512; s <<= 1) {
        int v = 0;
        if (t < 512 && t >= s) v = scan[t - s];
        __syncthreads();
        if (t < 512) scan[t] += v;
        __syncthreads();
    }
    for (int p = t; p < N; p += T) {
        float x = X[p * 3], y = X[p * 3 + 1], z = X[p * 3 + 2];
        int bid = bin_of(x, y, z);
        int pos = (scan[bid] - hist[bid]) + atomicAdd(&cnt[bid], 1);
        xp[(size_t)b * N + pos] = x;
        yp[(size_t)b * N + pos] = y;
        zp[(size_t)b * N + pos] = z;
        pid[(size_t)b * N + pos] = p;
    }
}

// ------------------------------------------- pruned FPS (level 1 only) ------
// Thread t owns 16 CONSECUTIVE binned points -> tight per-thread bbox.
// Per iteration: DPP wave argmax from CACHED (bv,bi) -> LDS atomicMax u64 ->
// barrier -> winner coords from LDS -> bbox lower-bound test; only threads
// whose bound can't exclude an update run the exact packed dmin update and
// recompute their local argmax. Skip is exact: d_box*0.999 > bv guarantees
// the fp sqdist of every owned point exceeds its dmin (1e-3 margin >> fp err).
template <int N, int M, int T>
__global__ __launch_bounds__(T, 1) void k_fps_pruned(
    const float* __restrict__ xp, const float* __restrict__ yp,
    const float* __restrict__ zp, const int* __restrict__ pidg,
    const float* __restrict__ xyz, int* __restrict__ idx_out) {
    constexpr int P = N / T;
    constexpr int P2 = P / 2;
    int b = blockIdx.x, t = threadIdx.x;
    const float* XP = xp + (size_t)b * N;
    const float* YP = yp + (size_t)b * N;
    const float* ZP = zp + (size_t)b * N;
    const int* PIDG = pidg + (size_t)b * N;
    __shared__ float sx[N], sy[N], sz[N];
    __shared__ int spid[N];
    __shared__ unsigned long long skey[3];
    f32x2 px[P2], py[P2], pz[P2], dmin[P2];
    float c0x = xyz[(size_t)b * N * 3 + 0];
    float c0y = xyz[(size_t)b * N * 3 + 1];
    float c0z = xyz[(size_t)b * N * 3 + 2];
    int base = t * P;
    float blx = 3e38f, bly = 3e38f, blz = 3e38f, bhx = -3e38f, bhy = -3e38f, bhz = -3e38f;
#pragma unroll
    for (int i = 0; i < P2; i++) {
        int p0 = base + 2 * i, p1 = p0 + 1;
        px[i] = f32x2{XP[p0], XP[p1]};
        py[i] = f32x2{YP[p0], YP[p1]};
        pz[i] = f32x2{ZP[p0], ZP[p1]};
        sx[p0] = px[i].x; sy[p0] = py[i].x; sz[p0] = pz[i].x;
        sx[p1] = px[i].y; sy[p1] = py[i].y; sz[p1] = pz[i].y;
        spid[p0] = PIDG[p0]; spid[p1] = PIDG[p1];
        blx = fminf(blx, fminf(px[i].x, px[i].y)); bhx = fmaxf(bhx, fmaxf(px[i].x, px[i].y));
        bly = fminf(bly, fminf(py[i].x, py[i].y)); bhy = fmaxf(bhy, fmaxf(py[i].x, py[i].y));
        blz = fminf(blz, fminf(pz[i].x, pz[i].y)); bhz = fmaxf(bhz, fmaxf(pz[i].x, pz[i].y));
        dmin[i] = sqdist2(px[i], py[i], pz[i], c0x, c0y, c0z);
    }
    if (t == 0) {
        idx_out[b * M] = 0;
        skey[0] = 0; skey[1] = 0; skey[2] = 0;
    }
    // local argmax (value tree + eq-scan min tree) -> cached (bv, bi)
    float bv;
    int bi;
    auto local_argmax = [&]() {
        f32x2 m2[P2];
#pragma unroll
        for (int i = 0; i < P2; i++) m2[i] = dmin[i];
#pragma unroll
        for (int s = P2 / 2; s >= 1; s >>= 1)
#pragma unroll
            for (int i = 0; i < s; i++) m2[i] = __builtin_elementwise_max(m2[i], m2[i + s]);
        bv = fmaxf(m2[0].x, m2[0].y);
        int ii[P];
#pragma unroll
        for (int i = 0; i < P; i++)
            ii[i] = (dmin[i >> 1][i & 1] == bv) ? (base + i) : 0x7fffffff;
#pragma unroll
        for (int s = P / 2; s >= 1; s >>= 1)
#pragma unroll
            for (int i = 0; i < s; i++) ii[i] = min(ii[i], ii[i + s]);
        bi = ii[0];
    };
    local_argmax();
    __syncthreads();
    int jm = 1;
    for (int j = 1; j < M; j++) {
        // wave argmax from cached (bv, bi): two single-op DPP chains
        float bw = bv;
        bw = fmaxf(bw, dpp_f<0x121>(bw));
        bw = fmaxf(bw, dpp_f<0x122>(bw));
        bw = fmaxf(bw, dpp_f<0x124>(bw));
        bw = fmaxf(bw, dpp_f<0x128>(bw));
        bw = fmaxf(bw, dpp_f<0x142>(bw));
        bw = fmaxf(bw, dpp_f<0x143>(bw));
        float bvw = __int_as_float(__builtin_amdgcn_readlane(__float_as_int(bw), 63));
        unsigned int im = (bv == bvw) ? (unsigned int)bi : 0xffffffffu;
        im = min(im, (unsigned int)dpp_i<0x121>((int)im));
        im = min(im, (unsigned int)dpp_i<0x122>((int)im));
        im = min(im, (unsigned int)dpp_i<0x124>((int)im));
        im = min(im, (unsigned int)dpp_i<0x128>((int)im));
        im = min(im, (unsigned int)dpp_i<0x142>((int)im));
        im = min(im, (unsigned int)dpp_i<0x143>((int)im));
        int biw = __builtin_amdgcn_readlane((int)im, 63);
        unsigned long long key =
            ((unsigned long long)__float_as_uint(bvw) << 32) | (unsigned int)~biw;
        if ((t & 63) == 0) atomicMax(&skey[jm], key);
        __syncthreads();
        unsigned long long gk = skey[jm];
        int gi = (int)~(unsigned int)gk;
        if (t == 0) {
            idx_out[b * M + j] = spid[gi];
            skey[jm == 0 ? 2 : jm - 1] = 0;
        }
        jm = (jm == 2) ? 0 : jm + 1;
        float cx = sx[gi], cy = sy[gi], cz = sz[gi];
        // conservative bbox lower bound on d(c, any owned point)
        float qx = fminf(fmaxf(cx, blx), bhx);
        float qy = fminf(fmaxf(cy, bly), bhy);
        float qz = fminf(fmaxf(cz, blz), bhz);
        float dxb = cx - qx, dyb = cy - qy, dzb = cz - qz;
        float db = dxb * dxb + dyb * dyb + dzb * dzb;
        if (!(db * 0.999f > bv)) {
#pragma unroll
            for (int i = 0; i < P2; i++)
                dmin[i] = __builtin_elementwise_min(
                    dmin[i], sqdist2(px[i], py[i], pz[i], cx, cy, cz));
            local_argmax();
        }
    }
}

// ------------------------------------------------------------ FPS body ------
// R11-proven path (used for levels 2-4).
template <int N, int M, int T>
DEV void fps_body(int b, int t, const float* __restrict__ xyz,
                  int* __restrict__ idx_out, char* smem) {
    constexpr int P = N / T;
    constexpr int P2 = P / 2;
    constexpr int W = T / 64;
    const float* X = xyz + (size_t)b * N * 3;
    float* sx = (float*)smem;
    float* sy = sx + N;
    float* sz = sy + N;
    unsigned long long* skey = (unsigned long long*)(smem + 12 * N);
    f32x2 px[P2], py[P2], pz[P2], dmin[P2];
    float c0x = X[0], c0y = X[1], c0z = X[2];
#pragma unroll
    for (int i = 0; i < P2; i++) {
        int p0 = (2 * i) * T + t, p1 = (2 * i + 1) * T + t;
        px[i] = f32x2{X[p0 * 3 + 0], X[p1 * 3 + 0]};
        py[i] = f32x2{X[p0 * 3 + 1], X[p1 * 3 + 1]};
        pz[i] = f32x2{X[p0 * 3 + 2], X[p1 * 3 + 2]};
        sx[p0] = px[i].x; sy[p0] = py[i].x; sz[p0] = pz[i].x;
        sx[p1] = px[i].y; sy[p1] = py[i].y; sz[p1] = pz[i].y;
        dmin[i] = sqdist2(px[i], py[i], pz[i], c0x, c0y, c0z);
    }
    if (t == 0) {
        idx_out[b * M] = 0;
        skey[0] = 0; skey[1] = 0; skey[2] = 0;
    }
    __syncthreads();
    int jm = 1;
    for (int j = 1; j < M; j++) {
        f32x2 m2[P2];
#pragma unroll
        for (int i = 0; i < P2; i++) m2[i] = dmin[i];
#pragma unroll
        for (int s = P2 / 2; s >= 1; s >>= 1)
#pragma unroll
            for (int i = 0; i < s; i++) m2[i] = __builtin_elementwise_max(m2[i], m2[i + s]);
        float bv = fmaxf(m2[0].x, m2[0].y);
        int ii[P];
#pragma unroll
        for (int i = 0; i < P; i++)
            ii[i] = (dmin[i >> 1][i & 1] == bv) ? (i * T + t) : 0x7fffffff;
#pragma unroll
        for (int s = P / 2; s >= 1; s >>= 1)
#pragma unroll
            for (int i = 0; i < s; i++) ii[i] = min(ii[i], ii[i + s]);
        int bi = ii[0];
        float bw = bv;
        bw = fmaxf(bw, dpp_f<0x121>(bw));
        bw = fmaxf(bw, dpp_f<0x122>(bw));
        bw = fmaxf(bw, dpp_f<0x124>(bw));
        bw = fmaxf(bw, dpp_f<0x128>(bw));
        bw = fmaxf(bw, dpp_f<0x142>(bw));
        bw = fmaxf(bw, dpp_f<0x143>(bw));
        float bvw = __int_as_float(__builtin_amdgcn_readlane(__float_as_int(bw), 63));
        unsigned int im = (bv == bvw) ? (unsigned int)bi : 0xffffffffu;
        im = min(im, (unsigned int)dpp_i<0x121>((int)im));
        im = min(im, (unsigned int)dpp_i<0x122>((int)im));
        im = min(im, (unsigned int)dpp_i<0x124>((int)im));
        im = min(im, (unsigned int)dpp_i<0x128>((int)im));
        im = min(im, (unsigned int)dpp_i<0x142>((int)im));
        im = min(im, (unsigned int)dpp_i<0x143>((int)im));
        int biw = __builtin_amdgcn_readlane((int)im, 63);
        int gi;
        if constexpr (W > 1) {
            unsigned long long key =
                ((unsigned long long)__float_as_uint(bvw) << 32) | (unsigned int)~biw;
            if ((t & 63) == 0) atomicMax(&skey[jm], key);
            __syncthreads();
            unsigned long long gk = skey[jm];
            gi = (int)~(unsigned int)gk;
            if (t == 0) skey[jm == 0 ? 2 : jm - 1] = 0;
            jm = (jm == 2) ? 0 : jm + 1;
        } else {
            gi = biw;
        }
        if (t == 0) idx_out[b * M + j] = gi;
        float cx = sx[gi], cy = sy[gi], cz = sz[gi];
#pragma unroll
        for (int i = 0; i < P2; i++)
            dmin[i] = __builtin_elementwise_min(
                dmin[i], sqdist2(px[i], py[i], pz[i], cx, cy, cz));
    }
}

template <int N, int M, int T>
__global__ __launch_bounds__(T, 1) void k_fps(const float* __restrict__ xyz,
                                              int* __restrict__ idx_out) {
    __shared__ __align__(16) char smem[12 * N + 24];
    fps_body<N, M, T>(blockIdx.x, threadIdx.x, xyz, idx_out, smem);
}

// -------------------------------------------------------------- gather ------
__global__ __launch_bounds__(256) void k_gather(const float* __restrict__ xyz_src,
                                                const int* __restrict__ idx,
                                                float* __restrict__ xyz_dst,
                                                int NS, int M) {
    int i = blockIdx.x * blockDim.x + threadIdx.x;
    if (i >= 2 * M) return;
    int b = i / M;
    int id = idx[i] & (NS - 1);
    xyz_dst[i * 3 + 0] = xyz_src[((size_t)b * NS + id) * 3 + 0];
    xyz_dst[i * 3 + 1] = xyz_src[((size_t)b * NS + id) * 3 + 1];
    xyz_dst[i * 3 + 2] = xyz_src[((size_t)b * NS + id) * 3 + 2];
}

// --------------------------------------------------------- SetConv body -----
template <int NS, int CF, int CMID, int COUT>
DEV void setconv_body(int q, int bb, int tid, int bdim,
                      const float* __restrict__ X, const unsigned short* __restrict__ F,
                      const float* __restrict__ C, const float* __restrict__ w1,
                      const float* __restrict__ b1, const float* __restrict__ w2,
                      const float* __restrict__ b2, unsigned short* __restrict__ fout,
                      float r2, int M, char* smem) {
    constexpr int CIN = 3 + CF;
    constexpr int K = 16;
    constexpr int M8 = CMID / 8;
    constexpr int O8 = COUT / 8;
    int blk = bb * M + q;
    const float* Xb = X + (size_t)bb * NS * 3;
    const unsigned short* Fb = F + (size_t)bb * NS * CF;
    int* s_n = (int*)smem;
    int* s_cntp = (int*)(smem + 64);
    float* s_h = (float*)(smem + 80);            // [K][CIN]
    float* s_mid = s_h + K * CIN;                // [K][CMID]
    float* s_pool = s_mid + K * CMID;            // [2][COUT]
    float cx = C[(size_t)blk * 3 + 0], cy = C[(size_t)blk * 3 + 1], cz = C[(size_t)blk * 3 + 2];
    if (tid < 64) {
        int lane = tid;
        int cnt = 0;
        for (int base = 0; base < NS; base += 64) {
            int p = base + lane;
            float d2 = sqdist(Xb[p * 3], Xb[p * 3 + 1], Xb[p * 3 + 2], cx, cy, cz);
            bool in = (d2 <= r2);
            unsigned long long msk = __ballot(in);
            if (in) {
                int pos = cnt + __popcll(msk & ((1ull << lane) - 1ull));
                if (pos < K) s_n[pos] = p;
            }
            cnt += __popcll(msk);
            if (cnt >= K) break;
        }
        if (lane == 0) *s_cntp = cnt < K ? cnt : K;
    }
    __syncthreads();
    int cnt = *s_cntp;
    if (tid >= cnt && tid < K) s_n[tid] = s_n[0];  // pad (center itself always hits)
    __syncthreads();
    for (int tIdx = tid; tIdx < K * CIN; tIdx += bdim) {
        int n = tIdx / CIN, c = tIdx % CIN;
        int gi = s_n[n];
        float v;
        if (c < 3) v = __fsub_rn(Xb[gi * 3 + c], (c == 0 ? cx : (c == 1 ? cy : cz)));
        else v = bf2f(Fb[(size_t)gi * CF + (c - 3)]);
        s_h[n * CIN + c] = v;
    }
    __syncthreads();
    if (tid < 128) {
        int n = tid >> 3, sub = tid & 7;
#pragma unroll
        for (int j = 0; j < M8; j++) {
            int m = sub * M8 + j;
            float acc = b1[m];
#pragma unroll 4
            for (int c = 0; c < CIN; c++) acc = fmaf(w1[m * CIN + c], s_h[n * CIN + c], acc);
            s_mid[n * CMID + m] = fmaxf(acc, 0.f);
        }
    }
    __syncthreads();
    if (tid < 128) {
        int n = tid >> 3, sub = tid & 7;
        float vals[O8];
#pragma unroll
        for (int j = 0; j < O8; j++) {
            int o = sub * O8 + j;
            float acc = b2[o];
#pragma unroll 4
            for (int c = 0; c < CMID; c++) acc = fmaf(w2[o * CMID + c], s_mid[n * CMID + c], acc);
            vals[j] = fmaxf(acc, 0.f);
        }
#pragma unroll
        for (int j = 0; j < O8; j++) {
            vals[j] = fmaxf(vals[j], __shfl_xor(vals[j], 8, 64));
            vals[j] = fmaxf(vals[j], __shfl_xor(vals[j], 16, 64));
            vals[j] = fmaxf(vals[j], __shfl_xor(vals[j], 32, 64));
        }
        int lw = tid & 63, wv = tid >> 6;
        if (lw < 8) {
#pragma unroll
            for (int j = 0; j < O8; j++) s_pool[wv * COUT + lw * O8 + j] = vals[j];
        }
    }
    __syncthreads();
    if (tid < 8) {
#pragma unroll
        for (int j = 0; j < O8; j++) {
            int o = tid * O8 + j;
            fout[(size_t)blk * COUT + o] = f2bf(fmaxf(s_pool[o], s_pool[COUT + o]));
        }
    }
}

template <int NS, int CF, int CMID, int COUT>
__global__ __launch_bounds__(128) void k_setconv(
    const float* __restrict__ X, const unsigned short* __restrict__ F,
    const float* __restrict__ C, const float* __restrict__ w1,
    const float* __restrict__ b1, const float* __restrict__ w2,
    const float* __restrict__ b2, unsigned short* __restrict__ fout,
    float r2, int M) {
    constexpr int K = 16;
    constexpr int CIN = 3 + CF;
    __shared__ __align__(16) char smem[80 + 4 * (K * CIN + K * CMID + 2 * COUT)];
    setconv_body<NS, CF, CMID, COUT>(blockIdx.x, blockIdx.y, threadIdx.x, blockDim.x,
                                     X, F, C, w1, b1, w2, b2, fout, r2, M, smem);
}

// --------------------------------------------- fused FPS + SetConv ----------
template <int N, int M, int T, int NS, int CF, int CMID, int COUT>
__global__ __launch_bounds__(T, 1) void k_fps_sc(
    const float* __restrict__ fxyz, int* __restrict__ idx_out,
    const float* __restrict__ X, const unsigned short* __restrict__ F,
    const float* __restrict__ C, const float* __restrict__ w1,
    const float* __restrict__ b1, const float* __restrict__ w2,
    const float* __restrict__ b2, unsigned short* __restrict__ fout,
    float r2, int Msc) {
    constexpr int K = 16;
    constexpr int CIN = 3 + CF;
    constexpr int FPS_B = 12 * N + 24;
    constexpr int SC_B = 80 + 4 * (K * CIN + K * CMID + 2 * COUT);
    constexpr int SB = FPS_B > SC_B ? FPS_B : SC_B;
    __shared__ __align__(16) char smem[SB];
    if (blockIdx.x < 2) {
        fps_body<N, M, T>(blockIdx.x, threadIdx.x, fxyz, idx_out, smem);
    } else {
        int lin = blockIdx.x - 2;
        int q = lin % Msc, bb = lin / Msc;
        setconv_body<NS, CF, CMID, COUT>(q, bb, threadIdx.x, blockDim.x,
                                         X, F, C, w1, b1, w2, b2, fout, r2, Msc, smem);
    }
}

// ------------------------------------------------------------ SetUpConv -----
template <int S, int CS, int CMID, int CD, int COUT, bool TRANS>
__global__ __launch_bounds__(64) void k_upconv(
    const float* __restrict__ SX, const float* __restrict__ DX,
    const void* __restrict__ SFv, const unsigned short* __restrict__ DF,
    const float* __restrict__ w1, const float* __restrict__ b1,
    const float* __restrict__ w2, const float* __restrict__ b2,
    float* __restrict__ out, int o_off, int ND) {
    constexpr int K = 8;
    constexpr int CIN = 3 + CS;
    constexpr int CIN2 = CMID + CD;
    constexpr int M8 = CMID / 8;
    int q = blockIdx.x, b = blockIdx.y;
    int blk = b * ND + q;
    int lane = threadIdx.x;
    const float* SXb = SX + (size_t)b * S * 3;
    float qx = DX[(size_t)blk * 3], qy = DX[(size_t)blk * 3 + 1], qz = DX[(size_t)blk * 3 + 2];
    __shared__ int s_k[K];
    __shared__ float s_h[K][CIN];
    __shared__ float s_in2[CIN2];
    float bd[K];
    int bi[K];
#pragma unroll
    for (int i = 0; i < K; i++) { bd[i] = 3.0e38f; bi[i] = 0x7fffffff; }
    for (int p = lane; p < S; p += 64) {
        float d2 = sqdist(SXb[p * 3], SXb[p * 3 + 1], SXb[p * 3 + 2], qx, qy, qz);
        if (d2 < bd[K - 1] || (d2 == bd[K - 1] && p < bi[K - 1])) {
            bd[K - 1] = d2; bi[K - 1] = p;
#pragma unroll
            for (int j = K - 1; j > 0; j--) {
                bool sw = (bd[j] < bd[j - 1]) || (bd[j] == bd[j - 1] && bi[j] < bi[j - 1]);
                if (sw) {
                    float tv = bd[j]; bd[j] = bd[j - 1]; bd[j - 1] = tv;
                    int ti = bi[j]; bi[j] = bi[j - 1]; bi[j - 1] = ti;
                }
            }
        }
    }
    for (int r = 0; r < K; r++) {
        float vv = bd[0];
        float bw = vv;
        bw = fminf(bw, dpp_f<0x121>(bw));
        bw = fminf(bw, dpp_f<0x122>(bw));
        bw = fminf(bw, dpp_f<0x124>(bw));
        bw = fminf(bw, dpp_f<0x128>(bw));
        bw = fminf(bw, dpp_f<0x142>(bw));
        bw = fminf(bw, dpp_f<0x143>(bw));
        float vw = __int_as_float(__builtin_amdgcn_readlane(__float_as_int(bw), 63));
        unsigned int im = (vv == vw) ? (unsigned int)bi[0] : 0xffffffffu;
        im = min(im, (unsigned int)dpp_i<0x121>((int)im));
        im = min(im, (unsigned int)dpp_i<0x122>((int)im));
        im = min(im, (unsigned int)dpp_i<0x124>((int)im));
        im = min(im, (unsigned int)dpp_i<0x128>((int)im));
        im = min(im, (unsigned int)dpp_i<0x142>((int)im));
        im = min(im, (unsigned int)dpp_i<0x143>((int)im));
        int iw = __builtin_amdgcn_readlane((int)im, 63);
        if (lane == 0) s_k[r] = iw;
        if (iw == bi[0]) {
#pragma unroll
            for (int j = 0; j < K - 1; j++) { bd[j] = bd[j + 1]; bi[j] = bi[j + 1]; }
            bd[K - 1] = 3.0e38f; bi[K - 1] = 0x7fffffff;
        }
    }
    __syncthreads();
    for (int tIdx = lane; tIdx < K * CIN; tIdx += 64) {
        int n = tIdx / CIN, c = tIdx % CIN;
        int gi = s_k[n];
        float v;
        if (c < 3) v = __fsub_rn(SXb[gi * 3 + c], (c == 0 ? qx : (c == 1 ? qy : qz)));
        else if (TRANS) v = ((const float*)SFv)[((size_t)b * CS + (c - 3)) * S + gi];
        else v = bf2f(((const unsigned short*)SFv)[((size_t)b * S + gi) * CS + (c - 3)]);
        s_h[n][c] = v;
    }
    for (int c = lane; c < CD; c += 64) s_in2[CMID + c] = bf2f(DF[(size_t)blk * CD + c]);
    __syncthreads();
    int n = lane >> 3, sub = lane & 7;
    float vals[M8];
#pragma unroll
    for (int j = 0; j < M8; j++) {
        int m = sub * M8 + j;
        float acc = b1[m];
#pragma unroll 4
        for (int c = 0; c < CIN; c++) acc = fmaf(w1[m * CIN + c], s_h[n][c], acc);
        vals[j] = fmaxf(acc, 0.f);
    }
#pragma unroll
    for (int j = 0; j < M8; j++) {
        vals[j] = fmaxf(vals[j], __shfl_xor(vals[j], 8, 64));
        vals[j] = fmaxf(vals[j], __shfl_xor(vals[j], 16, 64));
        vals[j] = fmaxf(vals[j], __shfl_xor(vals[j], 32, 64));
    }
    if (lane < 8) {
#pragma unroll
        for (int j = 0; j < M8; j++) s_in2[lane * M8 + j] = vals[j];
    }
    __syncthreads();
    for (int o = lane; o < COUT; o += 64) {
        float acc = b2[o];
#pragma unroll 4
        for (int c = 0; c < CIN2; c++) acc = fmaf(w2[o * CIN2 + c], s_in2[c], acc);
        out[o_off + ((size_t)b * COUT + o) * ND + q] = fmaxf(acc, 0.f);
    }
}

// ------------------------------------------------------------- finalize -----
__global__ __launch_bounds__(256) void k_finalize(
    const float* __restrict__ xyz1, const float* __restrict__ xyz2,
    const float* __restrict__ xyz3, const int* __restrict__ idx1,
    const int* __restrict__ idx2, const int* __restrict__ idx3,
    float* __restrict__ out) {
    int i = blockIdx.x * blockDim.x + threadIdx.x;
    const float* xs;
    const int* is;
    int M, ox, oi, j;
    if (i < 4096) { xs = xyz1; is = idx1; M = 2048; ox = O_X1; oi = O_I1; j = i; }
    else if (i < 5120) { xs = xyz2; is = idx2; M = 512; ox = O_X2; oi = O_I2; j = i - 4096; }
    else if (i < 5376) { xs = xyz3; is = idx3; M = 128; ox = O_X3; oi = O_I3; j = i - 5120; }
    else return;
    int b = j / M, m = j % M;
    out[ox + (b * 3 + 0) * M + m] = xs[j * 3 + 0];
    out[ox + (b * 3 + 1) * M + m] = xs[j * 3 + 1];
    out[ox + (b * 3 + 2) * M + m] = xs[j * 3 + 2];
    out[oi + j] = (float)is[j];
}

// ---------------------------------------------------------------- launch ----
extern "C" void kernel_launch(void* const* d_in, const int* in_sizes, int n_in,
                              void* d_out, int out_size, void* d_ws, size_t ws_size,
                              hipStream_t stream) {
    const float* pc = (const float*)d_in[0];
    const float* feat = (const float*)d_in[1];
    const float* w0 = (const float*)d_in[2];
    const float* b0v = (const float*)d_in[3];
    const float* sc1w1 = (const float*)d_in[4];  const float* sc1b1 = (const float*)d_in[5];
    const float* sc1w2 = (const float*)d_in[6];  const float* sc1b2 = (const float*)d_in[7];
    const float* sc2w1 = (const float*)d_in[8];  const float* sc2b1 = (const float*)d_in[9];
    const float* sc2w2 = (const float*)d_in[10]; const float* sc2b2 = (const float*)d_in[11];
    const float* sc3w1 = (const float*)d_in[12]; const float* sc3b1 = (const float*)d_in[13];
    const float* sc3w2 = (const float*)d_in[14]; const float* sc3b2 = (const float*)d_in[15];
    const float* sc4w1 = (const float*)d_in[16]; const float* sc4b1 = (const float*)d_in[17];
    const float* sc4w2 = (const float*)d_in[18]; const float* sc4b2 = (const float*)d_in[19];
    const float* up4w1 = (const float*)d_in[20]; const float* up4b1 = (const float*)d_in[21];
    const float* up4w2 = (const float*)d_in[22]; const float* up4b2 = (const float*)d_in[23];
    const float* up3w1 = (const float*)d_in[24]; const float* up3b1 = (const float*)d_in[25];
    const float* up3w2 = (const float*)d_in[26]; const float* up3b2 = (const float*)d_in[27];
    const float* up2w1 = (const float*)d_in[28]; const float* up2b1 = (const float*)d_in[29];
    const float* up2w2 = (const float*)d_in[30]; const float* up2b2 = (const float*)d_in[31];
    const float* up1w1 = (const float*)d_in[32]; const float* up1b1 = (const float*)d_in[33];
    const float* up1w2 = (const float*)d_in[34]; const float* up1b2 = (const float*)d_in[35];
    float* out = (float*)d_out;

    char* ws = (char*)d_ws;
    size_t off = 0;
    auto A = [&](size_t bytes) -> char* {
        char* p = ws + off;
        off += (bytes + 255) & ~(size_t)255;
        return p;
    };
    float* xyz  = (float*)A((size_t)2 * 8192 * 3 * 4);
    int* idx1   = (int*)A((size_t)2 * 2048 * 4);
    int* idx2   = (int*)A((size_t)2 * 512 * 4);
    int* idx3   = (int*)A((size_t)2 * 128 * 4);
    int* idx4   = (int*)A((size_t)2 * 64 * 4);
    float* xyz1 = (float*)A((size_t)2 * 2048 * 3 * 4);
    float* xyz2 = (float*)A((size_t)2 * 512 * 3 * 4);
    float* xyz3 = (float*)A((size_t)2 * 128 * 3 * 4);
    float* xyz4 = (float*)A((size_t)2 * 64 * 3 * 4);
    unsigned short* f0 = (unsigned short*)A((size_t)2 * 8192 * 32 * 2);
    unsigned short* f1 = (unsigned short*)A((size_t)2 * 2048 * 64 * 2);
    unsigned short* f2 = (unsigned short*)A((size_t)2 * 512 * 128 * 2);
    unsigned short* f3 = (unsigned short*)A((size_t)2 * 128 * 192 * 2);
    unsigned short* f4 = (unsigned short*)A((size_t)2 * 64 * 192 * 2);
    float* xp  = (float*)A((size_t)2 * 8192 * 4);
    float* yp  = (float*)A((size_t)2 * 8192 * 4);
    float* zp  = (float*)A((size_t)2 * 8192 * 4);
    int* pid   = (int*)A((size_t)2 * 8192 * 4);

    k_init<<<(2 * 8192 + 255) / 256, 256, 0, stream>>>(pc, feat, w0, b0v, xyz, f0);

    // ---- down path
    k_bin<8192, 512><<<2, 512, 0, stream>>>(xyz, xp, yp, zp, pid);
    k_fps_pruned<8192, 2048, 512><<<2, 512, 0, stream>>>(xp, yp, zp, pid, xyz, idx1);
    k_gather<<<16, 256, 0, stream>>>(xyz, idx1, xyz1, 8192, 2048);
    // fps level-2 (blocks 0-1) runs concurrently with setconv level-1
    k_fps_sc<2048, 512, 512, 8192, 32, 32, 64><<<2 + 2 * 2048, 512, 0, stream>>>(
        xyz1, idx2, xyz, f0, xyz1, sc1w1, sc1b1, sc1w2, sc1b2, f1, 0.25f, 2048);
    k_gather<<<4, 256, 0, stream>>>(xyz1, idx2, xyz2, 2048, 512);
    // fps level-3 + setconv level-2
    k_fps_sc<512, 128, 256, 2048, 64, 64, 128><<<2 + 2 * 512, 256, 0, stream>>>(
        xyz2, idx3, xyz1, f1, xyz2, sc2w1, sc2b1, sc2w2, sc2b2, f2, 1.0f, 512);
    k_gather<<<1, 256, 0, stream>>>(xyz2, idx3, xyz3, 512, 128);
    k_fps<128, 64, 64><<<2, 64, 0, stream>>>(xyz3, idx4);
    k_gather<<<1, 128, 0, stream>>>(xyz3, idx4, xyz4, 128, 64);
    k_setconv<512, 128, 128, 192><<<dim3(128, 2), 128, 0, stream>>>(
        xyz2, f2, xyz3, sc3w1, sc3b1, sc3w2, sc3b2, f3, 4.0f, 128);
    k_setconv<128, 192, 192, 192><<<dim3(64, 2), 128, 0, stream>>>(
        xyz3, f3, xyz4, sc4w1, sc4b1, sc4w2, sc4b2, f4, 16.0f, 64);

    // ---- up path (sequential deps; u-features live in final out regions)
    k_upconv<64, 192, 192, 192, 192, false><<<dim3(128, 2), 64, 0, stream>>>(
        xyz4, xyz3, f4, f3, up4w1, up4b1, up4w2, up4b2, out, O_U3, 128);
    k_upconv<128, 192, 128, 128, 128, true><<<dim3(512, 2), 64, 0, stream>>>(
        xyz3, xyz2, out + O_U3, f2, up3w1, up3b1, up3w2, up3b2, out, O_U2, 512);
    k_upconv<512, 128, 64, 64, 64, true><<<dim3(2048, 2), 64, 0, stream>>>(
        xyz2, xyz1, out + O_U2, f1, up2w1, up2b1, up2w2, up2b2, out, O_U1, 2048);
    k_upconv<2048, 64, 32, 32, 32, true><<<dim3(8192, 2), 64, 0, stream>>>(
        xyz1, xyz, out + O_U1, f0, up1w1, up1b1, up1w2, up1b2, out, O_U0, 8192);

    // ---- x/i outputs written last
    k_finalize<<<(5376 + 255) / 256, 256, 0, stream>>>(
        xyz1, xyz2, xyz3, idx1, idx2, idx3, out);
}